// Round 4
// baseline (1001.551 us; speedup 1.0000x reference)
//
#include <hip/hip_runtime.h>
#include <stdint.h>

typedef unsigned int u32;
typedef unsigned long long u64;

#define NN 32768
#define NE 262144
#define NC 128

// output element offsets (ALL FLOAT32)
#define O0 0u               // new_x [NN*128]
#define O1 4194304u         // cluster [NN]
#define O2 4227072u         // new_batch [NN]
#define O3 4259840u         // new_edge_score [NN]
#define O4 4292608u         // num_clusters [1]
#define O5 4292609u         // new_ei [2*NE]
#define O6 4816897u         // edge_valid [NE]
#define O7 5079041u         // e [NE]

#define HCAP (1u<<20)
#define NFULL 8
#define CNT0 8
#define MCAP 16384
#define MSB 16
#define MAXK 0xFFFFFFFFFFFFFFFFull

// ---------------- prep: u = W_t @ W_s (f64), c0 = b_t@W_s + b_s; zero counters ----
__global__ void ep_prep(const float* Wt, const float* Ws, const float* bt, const float* bs,
                        double* u, double* c0, u32* counters) {
    int i = threadIdx.x;
    double s = 0.0;
    for (int j = 0; j < NC; j++) s += (double)Wt[i*NC+j] * (double)Ws[j];
    u[i] = s;
    if (i == 0) {
        double c = 0.0;
        for (int j = 0; j < NC; j++) c += (double)bt[j] * (double)Ws[j];
        *c0 = c + (double)bs[0];
    }
    if (i < 64) counters[i] = 0u;
}

// ---------------- per-call state init ----------------
__global__ void ep_init(u64* bt0, u64* bt1, u32* avail, int* cl, u64* mkey) {
    int i = blockIdx.x*blockDim.x + threadIdx.x;
    if (i < NN) { bt0[i] = MAXK; bt1[i] = MAXK; cl[i] = -1; }
    if (i < NN/32) avail[i] = 0xFFFFFFFFu;
    if (i < MCAP) mkey[i] = MAXK;
}

// ---------------- per-node f64 dot y[v] = x[v,:]·u ----------------
__global__ void ep_ynode(const float* x, const double* u, double* y) {
    int gid = blockIdx.x*blockDim.x + threadIdx.x;
    int v = gid >> 6, lane = threadIdx.x & 63;
    if (v >= NN) return;
    double t = (double)x[v*NC+lane]*u[lane] + (double)x[v*NC+lane+64]*u[lane+64];
    for (int off = 32; off; off >>= 1) t += __shfl_down(t, off, 64);
    if (lane == 0) y[v] = t;
}

// ---------------- per-edge score + unique priority + frontier push ----------------
__global__ void ep_escore(const int* src, const int* dst, const float* rnd, const double* y,
                          const double* c0, u64* fkey, u64* fdat, u32* counters, float* out) {
    int e = blockIdx.x*blockDim.x + threadIdx.x;
    if (e >= NE) return;
    int s = src[e], d = dst[e];
    double z = y[s] + y[d] + *c0;
    double sc = 1.0/(1.0 + exp(-z));
    out[O7 + e] = (float)sc;
    u64 b = (u64)__double_as_longlong(z);
    u64 ord = (b & 0x8000000000000000ull) ? ~b : (b | 0x8000000000000000ull); // ascending z
    u64 P = ((~ord) & 0xFFFFFFFFFFFC0000ull) | (u64)(u32)e; // 46b score desc | 18b index (unique)
    if ((double)rnd[e] <= sc) {
        u32 p = atomicAdd(&counters[CNT0], 1u);
        fkey[p] = P;
        fdat[p] = ((u64)(u32)e << 30) | ((u64)(u32)s << 15) | (u64)(u32)d;
    }
}

// ---------------- matching rounds (unique-priority, ping-pong bestT) ----------------
__device__ __forceinline__ bool ep_bit(const u32* a, u32 v) { return (a[v>>5] >> (v&31)) & 1u; }

__global__ void ep_rA(const u64* fkey, const u64* fdat, const u32* cnt, u64* bt, const u32* avail) {
    u32 n = *cnt;
    for (u32 i = blockIdx.x*blockDim.x + threadIdx.x; i < n; i += 131072u) {
        u64 v = fdat[i];
        u32 s = (u32)((v>>15)&0x7FFF), d = (u32)(v&0x7FFF);
        if (ep_bit(avail, s) && ep_bit(avail, d)) {
            u64 P = fkey[i];
            atomicMin(&bt[s], P); atomicMin(&bt[d], P);
        }
    }
}

__global__ void ep_rB(const u64* fkey, const u64* fdat, const u32* cnt, u32* cntN,
                      u64* fkeyN, u64* fdatN, const u64* bt, u64* btN, u32* avail,
                      u64* mkey, u64* mpay, u32* counters) {
    u32 n = *cnt;
    for (u32 i = blockIdx.x*blockDim.x + threadIdx.x; i < n; i += 131072u) {
        u64 v = fdat[i];
        u32 s = (u32)((v>>15)&0x7FFF), d = (u32)(v&0x7FFF);
        if (!ep_bit(avail, s) || !ep_bit(avail, d)) continue; // dead
        u64 P = fkey[i];
        if (bt[s] == P && bt[d] == P) {
            u32 slot = atomicAdd(&counters[2], 1u);
            mkey[slot] = P; mpay[slot] = v;
            atomicAnd(&avail[s>>5], ~(1u<<(s&31)));
            atomicAnd(&avail[d>>5], ~(1u<<(d&31)));
        } else {
            u32 p = atomicAdd(cntN, 1u);
            fkeyN[p] = P; fdatN[p] = v;
            btN[s] = MAXK; btN[d] = MAXK;  // pre-reset next round's buffer
        }
    }
}

__global__ void __launch_bounds__(1024) ep_mtail(u64* ka, u64* da, u64* kb, u64* db,
                                                 const u32* cntIn, u64* bt, u32* avail,
                                                 u64* mkey, u64* mpay, u32* counters) {
    __shared__ u32 scnt;
    int t = threadIdx.x;
    u64 *ck = ka, *cd = da, *nk = kb, *nd = db;
    u32 cnt = *cntIn;
    for (int guard = 0; cnt != 0 && guard < 100000; guard++) {
        for (u32 i = t; i < cnt; i += 1024) { // phase A (atomic reads for freshness)
            u64 v = cd[i];
            u32 s = (u32)((v>>15)&0x7FFF), d = (u32)(v&0x7FFF);
            u32 as = atomicOr(&avail[s>>5], 0u), ad = atomicOr(&avail[d>>5], 0u);
            if (((as>>(s&31))&1u) && ((ad>>(d&31))&1u)) {
                u64 P = ck[i];
                atomicMin(&bt[s], P); atomicMin(&bt[d], P);
            }
        }
        if (t == 0) scnt = 0;
        __syncthreads();
        for (u32 i = t; i < cnt; i += 1024) { // phase B
            u64 v = cd[i];
            u32 s = (u32)((v>>15)&0x7FFF), d = (u32)(v&0x7FFF);
            u32 as = atomicOr(&avail[s>>5], 0u), ad = atomicOr(&avail[d>>5], 0u);
            if (!(((as>>(s&31))&1u) && ((ad>>(d&31))&1u))) continue;
            u64 P = ck[i];
            u64 bs = atomicOr(&bt[s], 0ull), bd = atomicOr(&bt[d], 0ull);
            if (bs == P && bd == P) {
                u32 slot = atomicAdd(&counters[2], 1u);
                mkey[slot] = P; mpay[slot] = v;
                atomicAnd(&avail[s>>5], ~(1u<<(s&31)));
                atomicAnd(&avail[d>>5], ~(1u<<(d&31)));
            } else {
                u32 p = atomicAdd(&scnt, 1u);
                nk[p] = P; nd[p] = v;
            }
        }
        __syncthreads();
        for (u32 i = t; i < cnt; i += 1024) { // phase C: reset
            u64 v = cd[i];
            u32 s = (u32)((v>>15)&0x7FFF), d = (u32)(v&0x7FFF);
            atomicExch(&bt[s], MAXK); atomicExch(&bt[d], MAXK);
        }
        __syncthreads();
        u32 nc2 = scnt;
        __syncthreads();
        cnt = nc2;
        u64* tp;
        tp = ck; ck = nk; nk = tp;
        tp = cd; cd = nd; nd = tp;
    }
}

// ---------------- small radix sort of matched list (16384 items, 6x8-bit LSD) ----------------
__global__ void ms_hist(const u64* key, u32* hist, int shift) {
    __shared__ u32 h[256];
    int t = threadIdx.x; // 64 threads, 16 blocks
    for (int i = t; i < 256; i += 64) h[i] = 0;
    __syncthreads();
    int base = blockIdx.x*1024 + t*16;
    for (int j = 0; j < 16; j++) {
        u32 dg = (u32)(key[base+j] >> shift) & 255u;
        atomicAdd(&h[dg], 1u);
    }
    __syncthreads();
    for (int i = t; i < 256; i += 64) hist[i*MSB + blockIdx.x] = h[i];
}

__global__ void ms_scan(u32* hist) { // 4096 entries, 1 block x 64 threads (1 wave)
    int t = threadIdx.x;
    int base = t*64;
    u32 s = 0;
    for (int j = 0; j < 64; j++) s += hist[base+j];
    u32 x = s;
    for (int off = 1; off < 64; off <<= 1) { u32 yv = __shfl_up(x, off, 64); if (t >= off) x += yv; }
    u32 run = x - s;
    for (int j = 0; j < 64; j++) { u32 tmp = hist[base+j]; hist[base+j] = run; run += tmp; }
}

__global__ void ms_scat(const u64* ki, const u64* pi, u64* ko, u64* po, const u32* hist, int shift) {
    __shared__ unsigned short m[256][64]; // 32 KiB
    int t = threadIdx.x; // 64 threads, 16 blocks
    for (int i = t; i < 256*64/2; i += 64) ((u32*)m)[i] = 0u;
    __syncthreads();
    int base = blockIdx.x*1024 + t*16;
    u64 kr[16]; u32 dg[16];
    #pragma unroll
    for (int j = 0; j < 16; j++) {
        kr[j] = ki[base+j];
        dg[j] = (u32)(kr[j] >> shift) & 255u;
        m[dg[j]][t]++;
    }
    __syncthreads();
    for (int k = 0; k < 4; k++) {
        int d = t*4 + k;
        u32 run = 0;
        for (int tt = 0; tt < 64; tt++) { u32 tmp = m[d][tt]; m[d][tt] = (unsigned short)run; run += tmp; }
    }
    __syncthreads();
    #pragma unroll
    for (int j = 0; j < 16; j++) {
        u32 d = dg[j];
        u32 pos = hist[d*MSB + blockIdx.x] + m[d][t];
        m[d][t]++;
        ko[pos] = kr[j];
        po[pos] = pi[base+j];
    }
}

// ---------------- cid assignment ----------------
__global__ void ep_emitM(const u64* mpay, const u32* counters, int* cl) {
    u32 i = blockIdx.x*blockDim.x + threadIdx.x;
    if (i >= counters[2]) return;
    u64 v = mpay[i];
    u32 s = (u32)((v>>15)&0x7FFF), d = (u32)(v&0x7FFF);
    cl[s] = (int)i; cl[d] = (int)i;
}

__global__ void ep_scanN(int* cl, u32* counters, float* out) {
    __shared__ u32 w[16];
    int t = threadIdx.x;
    int base = t*32;
    u32 s = 0;
    for (int j = 0; j < 32; j++) s += (cl[base+j] < 0) ? 1u : 0u;
    u32 x = s;
    for (int off = 1; off < 64; off <<= 1) { u32 y = __shfl_up(x, off, 64); if ((t&63) >= off) x += y; }
    if ((t&63) == 63) w[t>>6] = x;
    __syncthreads();
    if (t < 16) {
        u32 ww = w[t];
        for (int off = 1; off < 16; off <<= 1) { u32 y = __shfl_up(ww, off, 16); if (t >= off) ww += y; }
        w[t] = ww;
    }
    __syncthreads();
    u32 excl = ((t>>6) ? w[(t>>6)-1] : 0u) + x - s;
    u32 total = w[15];
    u32 nm = counters[2];
    if (t == 0) {
        counters[3] = nm + total;
        out[O4] = (float)(nm + total);
    }
    u32 run = nm + excl;
    for (int j = 0; j < 32; j++) { if (cl[base+j] < 0) cl[base+j] = (int)(run++); }
}

// ---------------- output init (only rows not otherwise written) ----------------
__global__ void ep_init_out(const u32* counters, float* out) {
    u32 i = blockIdx.x*blockDim.x + threadIdx.x;
    u32 nm = counters[2], ncl = counters[3];
    if (i < 4194304u) { if ((i>>7) >= ncl) out[O0 + i] = 0.0f; }
    if (i < 32768u) {
        if (i >= ncl) out[O2 + i] = 0.0f;
        if (i >= nm)  out[O3 + i] = 1.0f;
    }
}

__global__ void ep_out_nodes(const int* cl, const int* batch, const u32* counters, float* out) {
    int v = blockIdx.x*blockDim.x + threadIdx.x;
    if (v >= NN) return;
    int c = cl[v];
    out[O1 + v] = (float)c;
    if (c >= (int)counters[2]) out[O2 + c] = (float)batch[v]; // singleton
}

__global__ void ep_out_matched(const u64* mpay, const int* batch, const u32* counters, float* out) {
    u32 i = blockIdx.x*blockDim.x + threadIdx.x;
    if (i >= counters[2]) return;
    u64 v = mpay[i];
    u32 e = (u32)(v>>30), s = (u32)((v>>15)&0x7FFF), d = (u32)(v&0x7FFF);
    u32 mx = s > d ? s : d; // last-writer-wins = max node index
    out[O2 + i] = (float)batch[mx];
    out[O3 + i] = out[O7 + e];
}

// ---------------- new_x rows: 32 rows/block, 8 rows/wave, k-outer ----------------
__global__ void ep_newx_m(const float* x, const float* Wt, const float* bt,
                          const u64* mpay, const u32* counters, float* out) {
    __shared__ u64 ml[32];
    __shared__ float m[32][128];
    u32 nm = counters[2];
    u32 base = blockIdx.x * 32u;
    if (base >= nm) return;
    int t = threadIdx.x, lane = t & 63, wv = t >> 6;
    if (t < 32) { u32 r = base + (u32)t; ml[t] = (r < nm) ? mpay[r] : 0ull; }
    __syncthreads();
    for (int i = t; i < 4096; i += 256) {
        int r = i >> 7, k = i & 127;
        u64 v = ml[r];
        u32 s = (u32)((v>>15)&0x7FFF), d = (u32)(v&0x7FFF);
        m[r][k] = x[s*NC+k] + x[d*NC+k];
    }
    __syncthreads();
    float a0[8], a1[8];
    #pragma unroll
    for (int r = 0; r < 8; r++) { a0[r] = bt[lane]; a1[r] = bt[lane+64]; }
    for (int k = 0; k < 128; k++) {
        float w0 = Wt[k*NC+lane], w1 = Wt[k*NC+lane+64];
        #pragma unroll
        for (int r = 0; r < 8; r++) { float mm = m[wv*8+r][k]; a0[r] += mm*w0; a1[r] += mm*w1; }
    }
    #pragma unroll
    for (int r = 0; r < 8; r++) {
        u32 row = base + (u32)(wv*8 + r);
        if (row < nm) {
            out[O0 + (size_t)row*NC + lane]      = a0[r];
            out[O0 + (size_t)row*NC + lane + 64] = a1[r];
        }
    }
}

__global__ void ep_newx_s(const float* x, const float* Wt, const float* bt,
                          const int* cl, const u32* counters, float* out) {
    __shared__ int rows[32];
    __shared__ float m[32][128];
    __shared__ int anyS;
    u32 nm = counters[2];
    u32 base = blockIdx.x * 32u;
    int t = threadIdx.x, lane = t & 63, wv = t >> 6;
    if (t == 0) anyS = 0;
    __syncthreads();
    if (t < 32) {
        rows[t] = cl[base + t];
        if (rows[t] >= (int)nm) atomicOr(&anyS, 1);
    }
    __syncthreads();
    if (!anyS) return; // all 32 nodes matched — nothing to write
    for (int i = t; i < 4096; i += 256) {
        int r = i >> 7, k = i & 127;
        m[r][k] = 2.0f * x[(base + r)*NC + k];
    }
    __syncthreads();
    float a0[8], a1[8];
    #pragma unroll
    for (int r = 0; r < 8; r++) { a0[r] = bt[lane]; a1[r] = bt[lane+64]; }
    for (int k = 0; k < 128; k++) {
        float w0 = Wt[k*NC+lane], w1 = Wt[k*NC+lane+64];
        #pragma unroll
        for (int r = 0; r < 8; r++) { float mm = m[wv*8+r][k]; a0[r] += mm*w0; a1[r] += mm*w1; }
    }
    #pragma unroll
    for (int r = 0; r < 8; r++) {
        int row = rows[wv*8 + r];
        if (row >= (int)nm) { // singleton node
            out[O0 + (size_t)row*NC + lane]      = a0[r];
            out[O0 + (size_t)row*NC + lane + 64] = a1[r];
        }
    }
}

// ---------------- new_ei + edge_valid via min-index hash ----------------
__global__ void ep_newei(const int* src, const int* dst, const int* cl,
                         u32* tkey, u32* tmin, u32* eslot, float* out) {
    int e = blockIdx.x*blockDim.x + threadIdx.x;
    if (e >= NE) return;
    u32 cs = (u32)cl[src[e]], cd = (u32)cl[dst[e]];
    out[O5 + e]      = (float)cs;
    out[O5 + NE + e] = (float)cd;
    u32 key = (cs << 15) | cd;
    u32 slot = ((key * 2654435761u) >> 12) & (HCAP-1);
    while (true) {
        u32 k = tkey[slot];
        if (k == key) break;
        if (k == 0xFFFFFFFFu) {
            u32 old = atomicCAS(&tkey[slot], 0xFFFFFFFFu, key);
            if (old == 0xFFFFFFFFu || old == key) break;
        }
        slot = (slot + 1) & (HCAP-1);
    }
    eslot[e] = slot;
    atomicMin(&tmin[slot], (u32)e);
}

__global__ void ep_valid(const int* src, const int* dst, const int* cl,
                         const u32* tmin, const u32* eslot, float* out) {
    int e = blockIdx.x*blockDim.x + threadIdx.x;
    if (e >= NE) return;
    u32 cs = (u32)cl[src[e]], cd = (u32)cl[dst[e]];
    bool valid = (tmin[eslot[e]] == (u32)e) && (cs != cd);
    out[O6 + e] = valid ? 1.0f : 0.0f;
}

// =============================== host ===============================
extern "C" void kernel_launch(void* const* d_in, const int* in_sizes, int n_in,
                              void* d_out, int out_size, void* d_ws, size_t ws_size,
                              hipStream_t stream) {
    (void)in_sizes; (void)n_in; (void)out_size; (void)ws_size;
    const float* x    = (const float*)d_in[0];
    const int*   ei   = (const int*)d_in[1];
    const int*   src  = ei;
    const int*   dst  = ei + NE;
    const int*   batch= (const int*)d_in[2];
    const float* rnd  = (const float*)d_in[3];
    const float* Wt   = (const float*)d_in[4];
    const float* bt   = (const float*)d_in[5];
    const float* Ws   = (const float*)d_in[6];
    const float* bs   = (const float*)d_in[7];
    float* out = (float*)d_out;

    char* w = (char*)d_ws;
    double* u  = (double*)w;
    double* c0 = (double*)(w + 1024);
    u32* counters = (u32*)(w + 2048);
    size_t off = 4096;
    double* y   = (double*)(w + off); off += (size_t)NN*8;
    u64* fkeyA  = (u64*)(w + off); off += (size_t)NE*8;
    u64* fdatA  = (u64*)(w + off); off += (size_t)NE*8;
    u64* fkeyB  = (u64*)(w + off); off += (size_t)NE*8;
    u64* fdatB  = (u64*)(w + off); off += (size_t)NE*8;
    u64* mkeyA  = (u64*)(w + off); off += (size_t)MCAP*8;
    u64* mpayA  = (u64*)(w + off); off += (size_t)MCAP*8;
    u64* mkeyB  = (u64*)(w + off); off += (size_t)MCAP*8;
    u64* mpayB  = (u64*)(w + off); off += (size_t)MCAP*8;
    u64* bt0    = (u64*)(w + off); off += (size_t)NN*8;
    u64* bt1    = (u64*)(w + off); off += (size_t)NN*8;
    u32* avail  = (u32*)(w + off); off += NN/8;
    int* cl     = (int*)(w + off); off += (size_t)NN*4;
    u32* hist   = (u32*)(w + off); off += 4096*4;
    u32* tkey   = (u32*)(w + off); off += (size_t)HCAP*4;
    u32* tmin   = (u32*)(w + off); off += (size_t)HCAP*4;
    u32* eslot  = (u32*)(w + off); off += (size_t)NE*4;

    ep_prep<<<1, 128, 0, stream>>>(Wt, Ws, bt, bs, u, c0, counters);
    ep_init<<<128, 256, 0, stream>>>(bt0, bt1, avail, cl, mkeyA);
    hipMemsetAsync(tkey, 0xFF, (size_t)HCAP*4, stream);
    hipMemsetAsync(tmin, 0xFF, (size_t)HCAP*4, stream);

    ep_ynode<<<8192, 256, 0, stream>>>(x, u, y);
    ep_escore<<<1024, 256, 0, stream>>>(src, dst, rnd, y, c0, fkeyA, fdatA, counters, out);

    // matching: NFULL full-grid rounds (2 dispatches each) + single-block tail
    u64 *fk = fkeyA, *fd = fdatA, *fk2 = fkeyB, *fd2 = fdatB;
    u64 *bc = bt0, *bn = bt1;
    for (u32 rd = 0; rd < NFULL; rd++) {
        ep_rA<<<512, 256, 0, stream>>>(fk, fd, &counters[CNT0+rd], bc, avail);
        ep_rB<<<512, 256, 0, stream>>>(fk, fd, &counters[CNT0+rd], &counters[CNT0+rd+1],
                                       fk2, fd2, bc, bn, avail, mkeyA, mpayA, counters);
        u64* tp;
        tp = fk; fk = fk2; fk2 = tp;
        tp = fd; fd = fd2; fd2 = tp;
        tp = bc; bc = bn; bn = tp;
    }
    ep_mtail<<<1, 1024, 0, stream>>>(fk, fd, fk2, fd2, &counters[CNT0+NFULL],
                                     bc, avail, mkeyA, mpayA, counters);

    // sort matched list (padded to 16384) by unique priority: 6 passes over bits 16..63
    u64 *ki = mkeyA, *pi = mpayA, *ko = mkeyB, *po = mpayB;
    for (int p = 0; p < 6; p++) {
        int shift = 16 + p*8;
        ms_hist<<<MSB, 64, 0, stream>>>(ki, hist, shift);
        ms_scan<<<1, 64, 0, stream>>>(hist);
        ms_scat<<<MSB, 64, 0, stream>>>(ki, pi, ko, po, hist, shift);
        u64* tp;
        tp = ki; ki = ko; ko = tp;
        tp = pi; pi = po; po = tp;
    }
    // 6 passes (even) -> sorted data back in mkeyA/mpayA

    ep_emitM<<<64, 256, 0, stream>>>(mpayA, counters, cl);
    ep_scanN<<<1, 1024, 0, stream>>>(cl, counters, out);

    ep_init_out<<<16384, 256, 0, stream>>>(counters, out);
    ep_out_nodes<<<128, 256, 0, stream>>>(cl, batch, counters, out);
    ep_out_matched<<<64, 256, 0, stream>>>(mpayA, batch, counters, out);

    ep_newx_m<<<512, 256, 0, stream>>>(x, Wt, bt, mpayA, counters, out);
    ep_newx_s<<<1024, 256, 0, stream>>>(x, Wt, bt, cl, counters, out);

    ep_newei<<<1024, 256, 0, stream>>>(src, dst, cl, tkey, tmin, eslot, out);
    ep_valid<<<1024, 256, 0, stream>>>(src, dst, cl, tmin, eslot, out);
}

// Round 5
// 695.399 us; speedup vs baseline: 1.4403x; 1.4403x over previous
//
#include <hip/hip_runtime.h>
#include <stdint.h>

typedef unsigned int u32;
typedef unsigned long long u64;

#define NN 32768
#define NE 262144
#define NC 128

// output element offsets (ALL FLOAT32)
#define O0 0u               // new_x [NN*128]
#define O1 4194304u         // cluster [NN]
#define O2 4227072u         // new_batch [NN]
#define O3 4259840u         // new_edge_score [NN]
#define O4 4292608u         // num_clusters [1]
#define O5 4292609u         // new_ei [2*NE]
#define O6 4816897u         // edge_valid [NE]
#define O7 5079041u         // e [NE]

#define HCAP (1u<<20)
#define NFULL 8
#define CNT0 8
#define MCAP 16384
#define SCAP 32768   // merged sort capacity
#define SNB 32       // sort blocks (SCAP/1024)
#define MAXK 0xFFFFFFFFFFFFFFFFull
#define PREFLAG (1ull<<62)

// ---------------- prep: u = W_t @ W_s (f64), c0 = b_t@W_s + b_s; zero counters ----
__global__ void ep_prep(const float* Wt, const float* Ws, const float* bt, const float* bs,
                        double* u, double* c0, u32* counters) {
    int i = threadIdx.x;
    double s = 0.0;
    for (int j = 0; j < NC; j++) s += (double)Wt[i*NC+j] * (double)Ws[j];
    u[i] = s;
    if (i == 0) {
        double c = 0.0;
        for (int j = 0; j < NC; j++) c += (double)bt[j] * (double)Ws[j];
        *c0 = c + (double)bs[0];
    }
    if (i < 64) counters[i] = 0u;
}

// ---------------- per-call state init ----------------
__global__ void ep_init(u64* bt0, u64* bt1, u32* avail, int* cl) {
    int i = blockIdx.x*blockDim.x + threadIdx.x;
    if (i < NN) { bt0[i] = MAXK; bt1[i] = MAXK; cl[i] = -1; }
    if (i < NN/32) avail[i] = 0xFFFFFFFFu;
}

// ---------------- per-node f64 dot y[v] = x[v,:]·u ----------------
__global__ void ep_ynode(const float* x, const double* u, double* y) {
    int gid = blockIdx.x*blockDim.x + threadIdx.x;
    int v = gid >> 6, lane = threadIdx.x & 63;
    if (v >= NN) return;
    double t = (double)x[v*NC+lane]*u[lane] + (double)x[v*NC+lane+64]*u[lane+64];
    for (int off = 32; off; off >>= 1) t += __shfl_down(t, off, 64);
    if (lane == 0) y[v] = t;
}

// ---------------- per-edge score + unique priority + frontier push ----------------
__global__ void ep_escore(const int* src, const int* dst, const float* rnd, const double* y,
                          const double* c0, u64* fkey, u64* fdat, u32* counters, float* out) {
    int e = blockIdx.x*blockDim.x + threadIdx.x;
    if (e >= NE) return;
    int s = src[e], d = dst[e];
    double z = y[s] + y[d] + *c0;
    double sc = 1.0/(1.0 + exp(-z));
    out[O7 + e] = (float)sc;
    u64 b = (u64)__double_as_longlong(z);
    u64 ord = (b & 0x8000000000000000ull) ? ~b : (b | 0x8000000000000000ull); // ascending z
    u64 P = ((~ord) & 0xFFFFFFFFFFFC0000ull) | (u64)(u32)e; // 46b score desc | 18b index (unique)
    if ((double)rnd[e] <= sc) {
        u32 p = atomicAdd(&counters[CNT0], 1u);
        fkey[p] = P;
        fdat[p] = ((u64)(u32)e << 30) | ((u64)(u32)s << 15) | (u64)(u32)d;
    }
}

// ---------------- full-grid priority-matching rounds (ping-pong bestT) ----------------
__device__ __forceinline__ bool ep_bit(const u32* a, u32 v) { return (a[v>>5] >> (v&31)) & 1u; }

__global__ void ep_rA(const u64* fkey, const u64* fdat, const u32* cnt, u64* bt, const u32* avail) {
    u32 n = *cnt;
    for (u32 i = blockIdx.x*blockDim.x + threadIdx.x; i < n; i += 131072u) {
        u64 v = fdat[i];
        u32 s = (u32)((v>>15)&0x7FFF), d = (u32)(v&0x7FFF);
        if (ep_bit(avail, s) && ep_bit(avail, d)) {
            u64 P = fkey[i];
            atomicMin(&bt[s], P); atomicMin(&bt[d], P);
        }
    }
}

__global__ void ep_rB(const u64* fkey, const u64* fdat, const u32* cnt, u32* cntN,
                      u64* fkeyN, u64* fdatN, const u64* bt, u64* btN, u32* avail,
                      u64* mkey, u64* mpay, u32* counters) {
    u32 n = *cnt;
    for (u32 i = blockIdx.x*blockDim.x + threadIdx.x; i < n; i += 131072u) {
        u64 v = fdat[i];
        u32 s = (u32)((v>>15)&0x7FFF), d = (u32)(v&0x7FFF);
        if (!ep_bit(avail, s) || !ep_bit(avail, d)) continue; // dead
        u64 P = fkey[i];
        if (bt[s] == P && bt[d] == P) {
            u32 slot = atomicAdd(&counters[2], 1u);
            mkey[slot] = P; mpay[slot] = v;
            atomicAnd(&avail[s>>5], ~(1u<<(s&31)));
            atomicAnd(&avail[d>>5], ~(1u<<(d&31)));
        } else {
            u32 p = atomicAdd(cntN, 1u);
            fkeyN[p] = P; fdatN[p] = v;
            btN[s] = MAXK; btN[d] = MAXK;  // pre-reset next round's buffer
        }
    }
}

// ---------------- merge matched + remaining into one padded sort list ----------------
__global__ void ep_merge(const u64* mk, const u64* mp, const u64* fk, const u64* fd,
                         u32* counters, u64* ck, u64* cd2) {
    u32 i = blockIdx.x*blockDim.x + threadIdx.x; // SNB*1024 threads
    u32 nm0 = counters[2];
    u32 cr  = counters[CNT0+NFULL];
    if (i == 0) {
        u32 tot = nm0 + cr;
        counters[4] = tot > SCAP ? SCAP : tot;
    }
    u64 K = MAXK, D = 0;
    if (i < nm0) { K = mk[i]; D = mp[i] | PREFLAG; }
    else if (i < nm0 + cr && i < SCAP) { K = fk[i-nm0]; D = fd[i-nm0]; }
    ck[i] = K; cd2[i] = D;
}

// ---------------- radix sort of merged list (SCAP items, 6x8-bit LSD, bits 16..63) ----
__global__ void ms_hist(const u64* key, u32* hist, int shift) {
    __shared__ u32 h[256];
    int t = threadIdx.x; // 64 threads, SNB blocks
    for (int i = t; i < 256; i += 64) h[i] = 0;
    __syncthreads();
    int base = blockIdx.x*1024 + t*16;
    for (int j = 0; j < 16; j++) {
        u32 dg = (u32)(key[base+j] >> shift) & 255u;
        atomicAdd(&h[dg], 1u);
    }
    __syncthreads();
    for (int i = t; i < 256; i += 64) hist[i*SNB + blockIdx.x] = h[i];
}

__global__ void ms_scan(u32* hist) { // 256*SNB entries, 1 block x 64 threads
    int t = threadIdx.x;
    int per = 256*SNB/64;
    int base = t*per;
    u32 s = 0;
    for (int j = 0; j < per; j++) s += hist[base+j];
    u32 x = s;
    for (int off = 1; off < 64; off <<= 1) { u32 yv = __shfl_up(x, off, 64); if (t >= off) x += yv; }
    u32 run = x - s;
    for (int j = 0; j < per; j++) { u32 tmp = hist[base+j]; hist[base+j] = run; run += tmp; }
}

__global__ void ms_scat(const u64* ki, const u64* pi, u64* ko, u64* po, const u32* hist, int shift) {
    __shared__ unsigned short m[256][64]; // 32 KiB
    int t = threadIdx.x; // 64 threads, SNB blocks
    for (int i = t; i < 256*64/2; i += 64) ((u32*)m)[i] = 0u;
    __syncthreads();
    int base = blockIdx.x*1024 + t*16;
    u64 kr[16]; u32 dg[16];
    #pragma unroll
    for (int j = 0; j < 16; j++) {
        kr[j] = ki[base+j];
        dg[j] = (u32)(kr[j] >> shift) & 255u;
        m[dg[j]][t]++;
    }
    __syncthreads();
    for (int k = 0; k < 4; k++) {
        int d = t*4 + k;
        u32 run = 0;
        for (int tt = 0; tt < 64; tt++) { u32 tmp = m[d][tt]; m[d][tt] = (unsigned short)run; run += tmp; }
    }
    __syncthreads();
    #pragma unroll
    for (int j = 0; j < 16; j++) {
        u32 d = dg[j];
        u32 pos = hist[d*SNB + blockIdx.x] + m[d][t];
        m[d][t]++;
        ko[pos] = kr[j];
        po[pos] = pi[base+j];
    }
}

// ---------------- sorted sequential-chunk walk: tail matching + cid assignment ----------
__global__ void __launch_bounds__(1024) ep_stail(const u64* sk, const u64* sd, const u32* availG,
                                                 u32* counters, u64* Mlist, int* cl) {
    __shared__ u32 avail[1024];       // 32768 bits
    __shared__ u32 claim[16384];      // 64 KiB hashed claim table
    __shared__ u32 wsum[16];
    __shared__ u32 cidBaseSh;
    int t = threadIdx.x;
    avail[t] = availG[t];
    for (int j = t; j < 16384; j += 1024) claim[j] = 0xFFFFFFFFu;
    if (t == 0) cidBaseSh = 0;
    __syncthreads();
    u32 cntT = counters[4];
    for (u32 base = 0; base < cntT; base += 1024) {
        u32 i = base + t;
        bool have = i < cntT;
        u64 P = 0, v = 0; u32 s = 0, d = 0; bool pre = false;
        if (have) {
            P = sk[i]; v = sd[i];
            pre = (v & PREFLAG) != 0;
            v &= ~PREFLAG;
            s = (u32)((v>>15)&0x7FFF); d = (u32)(v&0x7FFF);
        }
        (void)P;
        // st: 0 = candidate, 1 = dead, 2 = matched
        int st;
        if (!have) st = 1;
        else if (pre) st = 2;
        else st = (((avail[s>>5]>>(s&31))&1u) && ((avail[d>>5]>>(d&31))&1u)) ? 0 : 1;
        // claim-resolution loop: min-active-lane always wins -> guaranteed progress
        for (int it = 0; __syncthreads_count(st == 0) > 0 && it < 200; it++) {
            u32 hs = s & 16383u, hd = d & 16383u;
            bool wrote = false;
            if (st == 0) { atomicMin(&claim[hs], (u32)t); atomicMin(&claim[hd], (u32)t); wrote = true; }
            __syncthreads();
            if (st == 0 && claim[hs] == (u32)t && claim[hd] == (u32)t) {
                st = 2;
                atomicAnd(&avail[s>>5], ~(1u<<(s&31)));
                atomicAnd(&avail[d>>5], ~(1u<<(d&31)));
            }
            __syncthreads();
            if (wrote) { claim[hs] = 0xFFFFFFFFu; claim[hd] = 0xFFFFFFFFu; }
            if (st == 0) {
                if (!((avail[s>>5]>>(s&31))&1u) || !((avail[d>>5]>>(d&31))&1u)) st = 1;
            }
        }
        // cid assignment in sorted (t) order via block scan
        u32 m = (st == 2) ? 1u : 0u;
        u32 x = m;
        for (int off = 1; off < 64; off <<= 1) { u32 y = __shfl_up(x, off, 64); if ((t&63) >= off) x += y; }
        if ((t&63) == 63) wsum[t>>6] = x;
        __syncthreads();
        if (t < 16) {
            u32 ww = wsum[t];
            for (int off = 1; off < 16; off <<= 1) { u32 y = __shfl_up(ww, off, 16); if (t >= off) ww += y; }
            wsum[t] = ww;
        }
        __syncthreads();
        u32 excl = ((t>>6) ? wsum[(t>>6)-1] : 0u) + x - m;
        u32 cid = cidBaseSh + excl;
        if (m) {
            Mlist[cid] = v;
            cl[s] = (int)cid; cl[d] = (int)cid;
        }
        __syncthreads();
        if (t == 1023) cidBaseSh = cid + m;
        __syncthreads();
    }
    if (t == 0) counters[2] = cidBaseSh; // final n_merged
}

// ---------------- singleton cid assignment ----------------
__global__ void ep_scanN(int* cl, u32* counters, float* out) {
    __shared__ u32 w[16];
    int t = threadIdx.x;
    int base = t*32;
    u32 s = 0;
    for (int j = 0; j < 32; j++) s += (cl[base+j] < 0) ? 1u : 0u;
    u32 x = s;
    for (int off = 1; off < 64; off <<= 1) { u32 y = __shfl_up(x, off, 64); if ((t&63) >= off) x += y; }
    if ((t&63) == 63) w[t>>6] = x;
    __syncthreads();
    if (t < 16) {
        u32 ww = w[t];
        for (int off = 1; off < 16; off <<= 1) { u32 y = __shfl_up(ww, off, 16); if (t >= off) ww += y; }
        w[t] = ww;
    }
    __syncthreads();
    u32 excl = ((t>>6) ? w[(t>>6)-1] : 0u) + x - s;
    u32 total = w[15];
    u32 nm = counters[2];
    if (t == 0) {
        counters[3] = nm + total;
        out[O4] = (float)(nm + total);
    }
    u32 run = nm + excl;
    for (int j = 0; j < 32; j++) { if (cl[base+j] < 0) cl[base+j] = (int)(run++); }
}

// ---------------- output init (only rows not otherwise written) ----------------
__global__ void ep_init_out(const u32* counters, float* out) {
    u32 i = blockIdx.x*blockDim.x + threadIdx.x;
    u32 nm = counters[2], ncl = counters[3];
    if (i < 4194304u) { if ((i>>7) >= ncl) out[O0 + i] = 0.0f; }
    if (i < 32768u) {
        if (i >= ncl) out[O2 + i] = 0.0f;
        if (i >= nm)  out[O3 + i] = 1.0f;
    }
}

__global__ void ep_out_nodes(const int* cl, const int* batch, const u32* counters, float* out) {
    int v = blockIdx.x*blockDim.x + threadIdx.x;
    if (v >= NN) return;
    int c = cl[v];
    out[O1 + v] = (float)c;
    if (c >= (int)counters[2]) out[O2 + c] = (float)batch[v]; // singleton
}

__global__ void ep_out_matched(const u64* Mlist, const int* batch, const u32* counters, float* out) {
    u32 i = blockIdx.x*blockDim.x + threadIdx.x;
    if (i >= counters[2]) return;
    u64 v = Mlist[i];
    u32 e = (u32)(v>>30), s = (u32)((v>>15)&0x7FFF), d = (u32)(v&0x7FFF);
    u32 mx = s > d ? s : d; // last-writer-wins = max node index
    out[O2 + i] = (float)batch[mx];
    out[O3 + i] = out[O7 + e];
}

// ---------------- new_x rows: 32 rows/block, 8 rows/wave, k-outer ----------------
__global__ void ep_newx_m(const float* x, const float* Wt, const float* bt,
                          const u64* Mlist, const u32* counters, float* out) {
    __shared__ u64 ml[32];
    __shared__ float m[32][128];
    u32 nm = counters[2];
    u32 base = blockIdx.x * 32u;
    if (base >= nm) return;
    int t = threadIdx.x, lane = t & 63, wv = t >> 6;
    if (t < 32) { u32 r = base + (u32)t; ml[t] = (r < nm) ? Mlist[r] : 0ull; }
    __syncthreads();
    for (int i = t; i < 4096; i += 256) {
        int r = i >> 7, k = i & 127;
        u64 v = ml[r];
        u32 s = (u32)((v>>15)&0x7FFF), d = (u32)(v&0x7FFF);
        m[r][k] = x[s*NC+k] + x[d*NC+k];
    }
    __syncthreads();
    float a0[8], a1[8];
    #pragma unroll
    for (int r = 0; r < 8; r++) { a0[r] = bt[lane]; a1[r] = bt[lane+64]; }
    for (int k = 0; k < 128; k++) {
        float w0 = Wt[k*NC+lane], w1 = Wt[k*NC+lane+64];
        #pragma unroll
        for (int r = 0; r < 8; r++) { float mm = m[wv*8+r][k]; a0[r] += mm*w0; a1[r] += mm*w1; }
    }
    #pragma unroll
    for (int r = 0; r < 8; r++) {
        u32 row = base + (u32)(wv*8 + r);
        if (row < nm) {
            out[O0 + (size_t)row*NC + lane]      = a0[r];
            out[O0 + (size_t)row*NC + lane + 64] = a1[r];
        }
    }
}

__global__ void ep_newx_s(const float* x, const float* Wt, const float* bt,
                          const int* cl, const u32* counters, float* out) {
    __shared__ int rows[32];
    __shared__ float m[32][128];
    __shared__ int anyS;
    u32 nm = counters[2];
    u32 base = blockIdx.x * 32u;
    int t = threadIdx.x, lane = t & 63, wv = t >> 6;
    if (t == 0) anyS = 0;
    __syncthreads();
    if (t < 32) {
        rows[t] = cl[base + t];
        if (rows[t] >= (int)nm) atomicOr(&anyS, 1);
    }
    __syncthreads();
    if (!anyS) return; // all 32 nodes matched — nothing to write
    for (int i = t; i < 4096; i += 256) {
        int r = i >> 7, k = i & 127;
        m[r][k] = 2.0f * x[(base + r)*NC + k];
    }
    __syncthreads();
    float a0[8], a1[8];
    #pragma unroll
    for (int r = 0; r < 8; r++) { a0[r] = bt[lane]; a1[r] = bt[lane+64]; }
    for (int k = 0; k < 128; k++) {
        float w0 = Wt[k*NC+lane], w1 = Wt[k*NC+lane+64];
        #pragma unroll
        for (int r = 0; r < 8; r++) { float mm = m[wv*8+r][k]; a0[r] += mm*w0; a1[r] += mm*w1; }
    }
    #pragma unroll
    for (int r = 0; r < 8; r++) {
        int row = rows[wv*8 + r];
        if (row >= (int)nm) { // singleton node
            out[O0 + (size_t)row*NC + lane]      = a0[r];
            out[O0 + (size_t)row*NC + lane + 64] = a1[r];
        }
    }
}

// ---------------- new_ei + edge_valid via min-index hash ----------------
__global__ void ep_newei(const int* src, const int* dst, const int* cl,
                         u32* tkey, u32* tmin, u32* eslot, float* out) {
    int e = blockIdx.x*blockDim.x + threadIdx.x;
    if (e >= NE) return;
    u32 cs = (u32)cl[src[e]], cd = (u32)cl[dst[e]];
    out[O5 + e]      = (float)cs;
    out[O5 + NE + e] = (float)cd;
    u32 key = (cs << 15) | cd;
    u32 slot = ((key * 2654435761u) >> 12) & (HCAP-1);
    while (true) {
        u32 k = tkey[slot];
        if (k == key) break;
        if (k == 0xFFFFFFFFu) {
            u32 old = atomicCAS(&tkey[slot], 0xFFFFFFFFu, key);
            if (old == 0xFFFFFFFFu || old == key) break;
        }
        slot = (slot + 1) & (HCAP-1);
    }
    eslot[e] = slot;
    atomicMin(&tmin[slot], (u32)e);
}

__global__ void ep_valid(const int* src, const int* dst, const int* cl,
                         const u32* tmin, const u32* eslot, float* out) {
    int e = blockIdx.x*blockDim.x + threadIdx.x;
    if (e >= NE) return;
    u32 cs = (u32)cl[src[e]], cd = (u32)cl[dst[e]];
    bool valid = (tmin[eslot[e]] == (u32)e) && (cs != cd);
    out[O6 + e] = valid ? 1.0f : 0.0f;
}

// =============================== host ===============================
extern "C" void kernel_launch(void* const* d_in, const int* in_sizes, int n_in,
                              void* d_out, int out_size, void* d_ws, size_t ws_size,
                              hipStream_t stream) {
    (void)in_sizes; (void)n_in; (void)out_size; (void)ws_size;
    const float* x    = (const float*)d_in[0];
    const int*   ei   = (const int*)d_in[1];
    const int*   src  = ei;
    const int*   dst  = ei + NE;
    const int*   batch= (const int*)d_in[2];
    const float* rnd  = (const float*)d_in[3];
    const float* Wt   = (const float*)d_in[4];
    const float* bt   = (const float*)d_in[5];
    const float* Ws   = (const float*)d_in[6];
    const float* bs   = (const float*)d_in[7];
    float* out = (float*)d_out;

    char* w = (char*)d_ws;
    double* u  = (double*)w;
    double* c0 = (double*)(w + 1024);
    u32* counters = (u32*)(w + 2048);
    size_t off = 4096;
    double* y   = (double*)(w + off); off += (size_t)NN*8;
    u64* fkeyA  = (u64*)(w + off); off += (size_t)NE*8;
    u64* fdatA  = (u64*)(w + off); off += (size_t)NE*8;
    u64* fkeyB  = (u64*)(w + off); off += (size_t)NE*8;
    u64* fdatB  = (u64*)(w + off); off += (size_t)NE*8;
    u64* mkeyA  = (u64*)(w + off); off += (size_t)MCAP*8;
    u64* mpayA  = (u64*)(w + off); off += (size_t)MCAP*8;
    u64* combK  = (u64*)(w + off); off += (size_t)SCAP*8;
    u64* combD  = (u64*)(w + off); off += (size_t)SCAP*8;
    u64* combK2 = (u64*)(w + off); off += (size_t)SCAP*8;
    u64* combD2 = (u64*)(w + off); off += (size_t)SCAP*8;
    u64* bt0    = (u64*)(w + off); off += (size_t)NN*8;
    u64* bt1    = (u64*)(w + off); off += (size_t)NN*8;
    u32* avail  = (u32*)(w + off); off += NN/8;
    int* cl     = (int*)(w + off); off += (size_t)NN*4;
    u64* Mlist  = (u64*)(w + off); off += (size_t)NN*8;
    u32* hist   = (u32*)(w + off); off += 256*SNB*4;
    u32* tkey   = (u32*)(w + off); off += (size_t)HCAP*4;
    u32* tmin   = (u32*)(w + off); off += (size_t)HCAP*4;
    u32* eslot  = (u32*)(w + off); off += (size_t)NE*4;

    ep_prep<<<1, 128, 0, stream>>>(Wt, Ws, bt, bs, u, c0, counters);
    ep_init<<<128, 256, 0, stream>>>(bt0, bt1, avail, cl);
    hipMemsetAsync(tkey, 0xFF, (size_t)HCAP*4, stream);
    hipMemsetAsync(tmin, 0xFF, (size_t)HCAP*4, stream);

    ep_ynode<<<8192, 256, 0, stream>>>(x, u, y);
    ep_escore<<<1024, 256, 0, stream>>>(src, dst, rnd, y, c0, fkeyA, fdatA, counters, out);

    // NFULL full-grid priority-matching rounds (2 dispatches each)
    u64 *fk = fkeyA, *fd = fdatA, *fk2 = fkeyB, *fd2 = fdatB;
    u64 *bc = bt0, *bn = bt1;
    for (u32 rd = 0; rd < NFULL; rd++) {
        ep_rA<<<512, 256, 0, stream>>>(fk, fd, &counters[CNT0+rd], bc, avail);
        ep_rB<<<512, 256, 0, stream>>>(fk, fd, &counters[CNT0+rd], &counters[CNT0+rd+1],
                                       fk2, fd2, bc, bn, avail, mkeyA, mpayA, counters);
        u64* tp;
        tp = fk; fk = fk2; fk2 = tp;
        tp = fd; fd = fd2; fd2 = tp;
        tp = bc; bc = bn; bn = tp;
    }

    // merge matched + remaining, sort by unique priority, then sorted-chunk walk
    ep_merge<<<SNB, 1024, 0, stream>>>(mkeyA, mpayA, fk, fd, counters, combK, combD);
    u64 *ki = combK, *pi = combD, *ko = combK2, *po = combD2;
    for (int p = 0; p < 6; p++) {
        int shift = 16 + p*8;
        ms_hist<<<SNB, 64, 0, stream>>>(ki, hist, shift);
        ms_scan<<<1, 64, 0, stream>>>(hist);
        ms_scat<<<SNB, 64, 0, stream>>>(ki, pi, ko, po, hist, shift);
        u64* tp;
        tp = ki; ki = ko; ko = tp;
        tp = pi; pi = po; po = tp;
    }
    // 6 passes (even) -> sorted list back in combK/combD
    ep_stail<<<1, 1024, 0, stream>>>(combK, combD, avail, counters, Mlist, cl);

    ep_scanN<<<1, 1024, 0, stream>>>(cl, counters, out);

    ep_init_out<<<16384, 256, 0, stream>>>(counters, out);
    ep_out_nodes<<<128, 256, 0, stream>>>(cl, batch, counters, out);
    ep_out_matched<<<64, 256, 0, stream>>>(Mlist, batch, counters, out);

    ep_newx_m<<<512, 256, 0, stream>>>(x, Wt, bt, Mlist, counters, out);
    ep_newx_s<<<1024, 256, 0, stream>>>(x, Wt, bt, cl, counters, out);

    ep_newei<<<1024, 256, 0, stream>>>(src, dst, cl, tkey, tmin, eslot, out);
    ep_valid<<<1024, 256, 0, stream>>>(src, dst, cl, tmin, eslot, out);
}

// Round 6
// 665.494 us; speedup vs baseline: 1.5050x; 1.0449x over previous
//
#include <hip/hip_runtime.h>
#include <stdint.h>

typedef unsigned int u32;
typedef unsigned long long u64;

#define NN 32768
#define NE 262144
#define NC 128

// output element offsets (ALL FLOAT32)
#define O0 0u               // new_x [NN*128]
#define O1 4194304u         // cluster [NN]
#define O2 4227072u         // new_batch [NN]
#define O3 4259840u         // new_edge_score [NN]
#define O4 4292608u         // num_clusters [1]
#define O5 4292609u         // new_ei [2*NE]
#define O6 4816897u         // edge_valid [NE]
#define O7 5079041u         // e [NE]

#define HCAP (1u<<19)
#define NFULL 8
#define CNT0 8
#define MCAP 16384
#define SCAP 32768   // merged sort capacity
#define SNB 32       // sort blocks (SCAP/1024)
#define MAXK 0xFFFFFFFFFFFFFFFFull
#define PREFLAG (1ull<<62)

// ---------------- prep: u = W_t @ W_s (f64), c0 = b_t@W_s + b_s; zero counters ----
__global__ void ep_prep(const float* Wt, const float* Ws, const float* bt, const float* bs,
                        double* u, double* c0, u32* counters) {
    int i = threadIdx.x;
    double s = 0.0;
    for (int j = 0; j < NC; j++) s += (double)Wt[i*NC+j] * (double)Ws[j];
    u[i] = s;
    if (i == 0) {
        double c = 0.0;
        for (int j = 0; j < NC; j++) c += (double)bt[j] * (double)Ws[j];
        *c0 = c + (double)bs[0];
    }
    if (i < 64) counters[i] = 0u;
}

// ---------------- per-call state init ----------------
__global__ void ep_init(u64* bt0, u64* bt1, u32* avail, int* cl) {
    int i = blockIdx.x*blockDim.x + threadIdx.x;
    if (i < NN) { bt0[i] = MAXK; bt1[i] = MAXK; cl[i] = -1; }
    if (i < NN/32) avail[i] = 0xFFFFFFFFu;
}

// ---------------- per-node f64 dot y[v] = x[v,:]·u ----------------
__global__ void ep_ynode(const float* x, const double* u, double* y) {
    int gid = blockIdx.x*blockDim.x + threadIdx.x;
    int v = gid >> 6, lane = threadIdx.x & 63;
    if (v >= NN) return;
    double t = (double)x[v*NC+lane]*u[lane] + (double)x[v*NC+lane+64]*u[lane+64];
    for (int off = 32; off; off >>= 1) t += __shfl_down(t, off, 64);
    if (lane == 0) y[v] = t;
}

// ---------------- per-edge score + unique priority + frontier push ----------------
__global__ void ep_escore(const int* src, const int* dst, const float* rnd, const double* y,
                          const double* c0, u64* fkey, u64* fdat, u32* counters, float* out) {
    int e = blockIdx.x*blockDim.x + threadIdx.x;
    if (e >= NE) return;
    int s = src[e], d = dst[e];
    double z = y[s] + y[d] + *c0;
    double sc = 1.0/(1.0 + exp(-z));
    out[O7 + e] = (float)sc;
    u64 b = (u64)__double_as_longlong(z);
    u64 ord = (b & 0x8000000000000000ull) ? ~b : (b | 0x8000000000000000ull); // ascending z
    u64 P = ((~ord) & 0xFFFFFFFFFFFC0000ull) | (u64)(u32)e; // 46b score desc | 18b index (unique)
    if ((double)rnd[e] <= sc) {
        u32 p = atomicAdd(&counters[CNT0], 1u);
        fkey[p] = P;
        fdat[p] = ((u64)(u32)e << 30) | ((u64)(u32)s << 15) | (u64)(u32)d;
    }
}

// ---------------- full-grid priority-matching rounds (ping-pong bestT) ----------------
__device__ __forceinline__ bool ep_bit(const u32* a, u32 v) { return (a[v>>5] >> (v&31)) & 1u; }

__global__ void ep_rA(const u64* fkey, const u64* fdat, const u32* cnt, u64* bt, const u32* avail) {
    u32 n = *cnt;
    for (u32 i = blockIdx.x*blockDim.x + threadIdx.x; i < n; i += 131072u) {
        u64 v = fdat[i];
        u32 s = (u32)((v>>15)&0x7FFF), d = (u32)(v&0x7FFF);
        if (ep_bit(avail, s) && ep_bit(avail, d)) {
            u64 P = fkey[i];
            atomicMin(&bt[s], P); atomicMin(&bt[d], P);
        }
    }
}

__global__ void ep_rB(const u64* fkey, const u64* fdat, const u32* cnt, u32* cntN,
                      u64* fkeyN, u64* fdatN, const u64* bt, u64* btN, u32* avail,
                      u64* mkey, u64* mpay, u32* counters) {
    u32 n = *cnt;
    for (u32 i = blockIdx.x*blockDim.x + threadIdx.x; i < n; i += 131072u) {
        u64 v = fdat[i];
        u32 s = (u32)((v>>15)&0x7FFF), d = (u32)(v&0x7FFF);
        if (!ep_bit(avail, s) || !ep_bit(avail, d)) continue; // dead
        u64 P = fkey[i];
        if (bt[s] == P && bt[d] == P) {
            u32 slot = atomicAdd(&counters[2], 1u);
            mkey[slot] = P; mpay[slot] = v;
            atomicAnd(&avail[s>>5], ~(1u<<(s&31)));
            atomicAnd(&avail[d>>5], ~(1u<<(d&31)));
        } else {
            u32 p = atomicAdd(cntN, 1u);
            fkeyN[p] = P; fdatN[p] = v;
            btN[s] = MAXK; btN[d] = MAXK;  // pre-reset next round's buffer
        }
    }
}

// ---------------- merge matched + remaining into one padded sort list ----------------
__global__ void ep_merge(const u64* mk, const u64* mp, const u64* fk, const u64* fd,
                         u32* counters, u64* ck, u64* cd2) {
    u32 i = blockIdx.x*blockDim.x + threadIdx.x; // SNB*1024 threads
    u32 nm0 = counters[2];
    u32 cr  = counters[CNT0+NFULL];
    if (i == 0) {
        u32 tot = nm0 + cr;
        counters[4] = tot > SCAP ? SCAP : tot;
    }
    u64 K = MAXK, D = 0;
    if (i < nm0) { K = mk[i]; D = mp[i] | PREFLAG; }
    else if (i < nm0 + cr && i < SCAP) { K = fk[i-nm0]; D = fd[i-nm0]; }
    ck[i] = K; cd2[i] = D;
}

// ---------------- radix sort of merged list (SCAP items, 6x8-bit LSD, bits 16..63) ----
__global__ void ms_hist(const u64* key, u32* hist, int shift) {
    __shared__ u32 h[256];
    int t = threadIdx.x; // 64 threads, SNB blocks
    for (int i = t; i < 256; i += 64) h[i] = 0;
    __syncthreads();
    int base = blockIdx.x*1024 + t*16;
    for (int j = 0; j < 16; j++) {
        u32 dg = (u32)(key[base+j] >> shift) & 255u;
        atomicAdd(&h[dg], 1u);
    }
    __syncthreads();
    for (int i = t; i < 256; i += 64) hist[i*SNB + blockIdx.x] = h[i];
}

__global__ void ms_scan(u32* hist) { // 256*SNB entries, 1 block x 64 threads
    int t = threadIdx.x;
    int per = 256*SNB/64;
    int base = t*per;
    u32 s = 0;
    for (int j = 0; j < per; j++) s += hist[base+j];
    u32 x = s;
    for (int off = 1; off < 64; off <<= 1) { u32 yv = __shfl_up(x, off, 64); if (t >= off) x += yv; }
    u32 run = x - s;
    for (int j = 0; j < per; j++) { u32 tmp = hist[base+j]; hist[base+j] = run; run += tmp; }
}

__global__ void ms_scat(const u64* ki, const u64* pi, u64* ko, u64* po, const u32* hist, int shift) {
    __shared__ unsigned short m[256][64]; // 32 KiB
    int t = threadIdx.x; // 64 threads, SNB blocks
    for (int i = t; i < 256*64/2; i += 64) ((u32*)m)[i] = 0u;
    __syncthreads();
    int base = blockIdx.x*1024 + t*16;
    u64 kr[16]; u32 dg[16];
    #pragma unroll
    for (int j = 0; j < 16; j++) {
        kr[j] = ki[base+j];
        dg[j] = (u32)(kr[j] >> shift) & 255u;
        m[dg[j]][t]++;
    }
    __syncthreads();
    for (int k = 0; k < 4; k++) {
        int d = t*4 + k;
        u32 run = 0;
        for (int tt = 0; tt < 64; tt++) { u32 tmp = m[d][tt]; m[d][tt] = (unsigned short)run; run += tmp; }
    }
    __syncthreads();
    #pragma unroll
    for (int j = 0; j < 16; j++) {
        u32 d = dg[j];
        u32 pos = hist[d*SNB + blockIdx.x] + m[d][t];
        m[d][t]++;
        ko[pos] = kr[j];
        po[pos] = pi[base+j];
    }
}

// ---------------- candidate compaction over sorted list ----------------
__global__ void ep_csum(const u64* sd, const u32* counters, u32* mflag, u32* csums) {
    u32 i = blockIdx.x*1024 + threadIdx.x;
    u32 cnt = counters[4];
    u64 v = sd[i];
    bool pre = (i < cnt) && ((v & PREFLAG) != 0);
    bool cand = (i < cnt) && !pre;
    mflag[i] = pre ? 1u : 0u;
    int c = __syncthreads_count(cand ? 1 : 0);
    if (threadIdx.x == 0) csums[blockIdx.x] = (u32)c;
}

__global__ void ep_cscan(u32* csums, u32* counters, int which) { // scans 32 values, 1 wave
    int t = threadIdx.x; // 64
    u32 v = (t < SNB) ? csums[t] : 0u;
    u32 x = v;
    for (int off = 1; off < 64; off <<= 1) { u32 y = __shfl_up(x, off, 64); if (t >= off) x += y; }
    if (t < SNB) csums[t] = x - v;
    if (t == SNB-1) counters[which] = x;
}

__global__ void ep_cemit(const u64* sd, const u32* counters, const u32* csums, u32* candIdx) {
    __shared__ u32 w[16];
    int t = threadIdx.x;
    u32 i = blockIdx.x*1024 + t;
    u32 cnt = counters[4];
    u64 v = sd[i];
    bool pre = (i < cnt) && ((v & PREFLAG) != 0);
    u32 c = ((i < cnt) && !pre) ? 1u : 0u;
    u32 x = c;
    for (int off = 1; off < 64; off <<= 1) { u32 y = __shfl_up(x, off, 64); if ((t&63) >= off) x += y; }
    if ((t&63) == 63) w[t>>6] = x;
    __syncthreads();
    if (t < 16) {
        u32 ww = w[t];
        for (int off = 1; off < 16; off <<= 1) { u32 y = __shfl_up(ww, off, 16); if (t >= off) ww += y; }
        w[t] = ww;
    }
    __syncthreads();
    u32 excl = ((t>>6) ? w[(t>>6)-1] : 0u) + x - c;
    if (c) candIdx[csums[blockIdx.x] + excl] = i;
}

// ---------------- candidate-only sorted claim walk (single block, LDS) ----------------
__global__ void __launch_bounds__(1024) ep_walk(const u64* sd, const u32* candIdx,
                                                const u32* counters, const u32* availG,
                                                u32* mflag) {
    __shared__ u32 avail[1024];       // 32768 bits
    __shared__ u32 claim[16384];      // 64 KiB claim table (node & 16383)
    int t = threadIdx.x;
    avail[t] = availG[t];
    for (int j = t; j < 16384; j += 1024) claim[j] = 0xFFFFFFFFu;
    __syncthreads();
    u32 ncand = counters[5];
    for (u32 base = 0; base < ncand; base += 1024) {
        u32 j = base + t;
        bool have = j < ncand;
        u32 i = 0, s = 0, d = 0;
        if (have) {
            i = candIdx[j];
            u64 v = sd[i];
            s = (u32)((v>>15)&0x7FFF); d = (u32)(v&0x7FFF);
        }
        // st: 0 = candidate, 1 = dead, 2 = matched
        int st;
        if (!have) st = 1;
        else st = (((avail[s>>5]>>(s&31))&1u) && ((avail[d>>5]>>(d&31))&1u)) ? 0 : 1;
        for (int it = 0; __syncthreads_count(st == 0) > 0 && it < 300; it++) {
            u32 hs = s & 16383u, hd = d & 16383u;
            bool wrote = false;
            if (st == 0) { atomicMin(&claim[hs], (u32)t); atomicMin(&claim[hd], (u32)t); wrote = true; }
            __syncthreads();
            if (st == 0 && claim[hs] == (u32)t && claim[hd] == (u32)t) {
                st = 2;
                atomicAnd(&avail[s>>5], ~(1u<<(s&31)));
                atomicAnd(&avail[d>>5], ~(1u<<(d&31)));
            }
            __syncthreads();
            if (wrote) { claim[hs] = 0xFFFFFFFFu; claim[hd] = 0xFFFFFFFFu; }
            if (st == 0) {
                if (!((avail[s>>5]>>(s&31))&1u) || !((avail[d>>5]>>(d&31))&1u)) st = 1;
            }
        }
        if (st == 2) mflag[i] = 1u;
        __syncthreads();
    }
}

// ---------------- cid assignment: parallel scan over match flags ----------------
__global__ void ep_msum(const u32* mflag, u32* msums) {
    u32 i = blockIdx.x*1024 + threadIdx.x;
    int c = __syncthreads_count(mflag[i] != 0 ? 1 : 0);
    if (threadIdx.x == 0) msums[blockIdx.x] = (u32)c;
}

__global__ void ep_memit(const u64* sd, const u32* mflag, const u32* msums,
                         const int* batch, u64* Mlist, int* cl, float* out) {
    __shared__ u32 w[16];
    int t = threadIdx.x;
    u32 i = blockIdx.x*1024 + t;
    u32 m = mflag[i];
    u32 x = m;
    for (int off = 1; off < 64; off <<= 1) { u32 y = __shfl_up(x, off, 64); if ((t&63) >= off) x += y; }
    if ((t&63) == 63) w[t>>6] = x;
    __syncthreads();
    if (t < 16) {
        u32 ww = w[t];
        for (int off = 1; off < 16; off <<= 1) { u32 y = __shfl_up(ww, off, 16); if (t >= off) ww += y; }
        w[t] = ww;
    }
    __syncthreads();
    u32 excl = ((t>>6) ? w[(t>>6)-1] : 0u) + x - m;
    if (m) {
        u32 cid = msums[blockIdx.x] + excl;
        u64 v = sd[i] & ~PREFLAG;
        u32 e = (u32)(v>>30), s = (u32)((v>>15)&0x7FFF), d = (u32)(v&0x7FFF);
        Mlist[cid] = v;
        cl[s] = (int)cid; cl[d] = (int)cid;
        u32 mx = s > d ? s : d; // last-writer-wins = max node index
        out[O2 + cid] = (float)batch[mx];
        out[O3 + cid] = out[O7 + e];
    }
}

// ---------------- singleton cid assignment + compacted singleton list ----------------
__global__ void ep_scanN(int* cl, u32* counters, u32* slist, float* out) {
    __shared__ u32 w[16];
    int t = threadIdx.x;
    int base = t*32;
    u32 s = 0;
    for (int j = 0; j < 32; j++) s += (cl[base+j] < 0) ? 1u : 0u;
    u32 x = s;
    for (int off = 1; off < 64; off <<= 1) { u32 y = __shfl_up(x, off, 64); if ((t&63) >= off) x += y; }
    if ((t&63) == 63) w[t>>6] = x;
    __syncthreads();
    if (t < 16) {
        u32 ww = w[t];
        for (int off = 1; off < 16; off <<= 1) { u32 y = __shfl_up(ww, off, 16); if (t >= off) ww += y; }
        w[t] = ww;
    }
    __syncthreads();
    u32 excl = ((t>>6) ? w[(t>>6)-1] : 0u) + x - s;
    u32 total = w[15];
    u32 nm = counters[2];
    if (t == 0) {
        counters[3] = nm + total;
        counters[6] = total;
        out[O4] = (float)(nm + total);
    }
    u32 run = nm + excl;
    for (int j = 0; j < 32; j++) {
        if (cl[base+j] < 0) {
            slist[run - nm] = (u32)(base + j);
            cl[base+j] = (int)(run++);
        }
    }
}

// ---------------- output init (only rows not otherwise written) ----------------
__global__ void ep_init_out(const u32* counters, float* out) {
    u32 i = blockIdx.x*blockDim.x + threadIdx.x;
    u32 nm = counters[2], ncl = counters[3];
    if (i < 4194304u) { if ((i>>7) >= ncl) out[O0 + i] = 0.0f; }
    if (i < 32768u) {
        if (i >= ncl) out[O2 + i] = 0.0f;
        if (i >= nm)  out[O3 + i] = 1.0f;
    }
}

__global__ void ep_out_nodes(const int* cl, const int* batch, const u32* counters, float* out) {
    int v = blockIdx.x*blockDim.x + threadIdx.x;
    if (v >= NN) return;
    int c = cl[v];
    out[O1 + v] = (float)c;
    if (c >= (int)counters[2]) out[O2 + c] = (float)batch[v]; // singleton
}

// ---------------- new_x rows: 32 rows/block, 8 rows/wave, k-outer ----------------
__global__ void ep_newx_m(const float* x, const float* Wt, const float* bt,
                          const u64* Mlist, const u32* counters, float* out) {
    __shared__ u64 ml[32];
    __shared__ float m[32][128];
    u32 nm = counters[2];
    u32 base = blockIdx.x * 32u;
    if (base >= nm) return;
    int t = threadIdx.x, lane = t & 63, wv = t >> 6;
    if (t < 32) { u32 r = base + (u32)t; ml[t] = (r < nm) ? Mlist[r] : 0ull; }
    __syncthreads();
    for (int i = t; i < 4096; i += 256) {
        int r = i >> 7, k = i & 127;
        u64 v = ml[r];
        u32 s = (u32)((v>>15)&0x7FFF), d = (u32)(v&0x7FFF);
        m[r][k] = x[s*NC+k] + x[d*NC+k];
    }
    __syncthreads();
    float a0[8], a1[8];
    #pragma unroll
    for (int r = 0; r < 8; r++) { a0[r] = bt[lane]; a1[r] = bt[lane+64]; }
    for (int k = 0; k < 128; k++) {
        float w0 = Wt[k*NC+lane], w1 = Wt[k*NC+lane+64];
        #pragma unroll
        for (int r = 0; r < 8; r++) { float mm = m[wv*8+r][k]; a0[r] += mm*w0; a1[r] += mm*w1; }
    }
    #pragma unroll
    for (int r = 0; r < 8; r++) {
        u32 row = base + (u32)(wv*8 + r);
        if (row < nm) {
            out[O0 + (size_t)row*NC + lane]      = a0[r];
            out[O0 + (size_t)row*NC + lane + 64] = a1[r];
        }
    }
}

__global__ void ep_newx_s(const float* x, const float* Wt, const float* bt,
                          const u32* slist, const u32* counters, float* out) {
    __shared__ u32 nodes[32];
    __shared__ float m[32][128];
    u32 sc = counters[6];
    u32 nm = counters[2];
    u32 base = blockIdx.x * 32u;
    if (base >= sc) return;
    int t = threadIdx.x, lane = t & 63, wv = t >> 6;
    if (t < 32) { u32 p = base + (u32)t; nodes[t] = (p < sc) ? slist[p] : slist[sc-1]; }
    __syncthreads();
    for (int i = t; i < 4096; i += 256) {
        int r = i >> 7, k = i & 127;
        m[r][k] = 2.0f * x[nodes[r]*NC + k];
    }
    __syncthreads();
    float a0[8], a1[8];
    #pragma unroll
    for (int r = 0; r < 8; r++) { a0[r] = bt[lane]; a1[r] = bt[lane+64]; }
    for (int k = 0; k < 128; k++) {
        float w0 = Wt[k*NC+lane], w1 = Wt[k*NC+lane+64];
        #pragma unroll
        for (int r = 0; r < 8; r++) { float mm = m[wv*8+r][k]; a0[r] += mm*w0; a1[r] += mm*w1; }
    }
    #pragma unroll
    for (int r = 0; r < 8; r++) {
        u32 p = base + (u32)(wv*8 + r);
        if (p < sc) {
            u32 row = nm + p;
            out[O0 + (size_t)row*NC + lane]      = a0[r];
            out[O0 + (size_t)row*NC + lane + 64] = a1[r];
        }
    }
}

// ---------------- new_ei + edge_valid via min-index hash ----------------
__global__ void ep_newei(const int* src, const int* dst, const int* cl,
                         u32* tkey, u32* tmin, u32* eslot, float* out) {
    int e = blockIdx.x*blockDim.x + threadIdx.x;
    if (e >= NE) return;
    u32 cs = (u32)cl[src[e]], cd = (u32)cl[dst[e]];
    out[O5 + e]      = (float)cs;
    out[O5 + NE + e] = (float)cd;
    u32 key = (cs << 15) | cd;
    u32 slot = ((key * 2654435761u) >> 11) & (HCAP-1);
    while (true) {
        u32 k = tkey[slot];
        if (k == key) break;
        if (k == 0xFFFFFFFFu) {
            u32 old = atomicCAS(&tkey[slot], 0xFFFFFFFFu, key);
            if (old == 0xFFFFFFFFu || old == key) break;
        }
        slot = (slot + 1) & (HCAP-1);
    }
    eslot[e] = slot;
    atomicMin(&tmin[slot], (u32)e);
}

__global__ void ep_valid(const int* src, const int* dst, const int* cl,
                         const u32* tmin, const u32* eslot, float* out) {
    int e = blockIdx.x*blockDim.x + threadIdx.x;
    if (e >= NE) return;
    u32 cs = (u32)cl[src[e]], cd = (u32)cl[dst[e]];
    bool valid = (tmin[eslot[e]] == (u32)e) && (cs != cd);
    out[O6 + e] = valid ? 1.0f : 0.0f;
}

// =============================== host ===============================
extern "C" void kernel_launch(void* const* d_in, const int* in_sizes, int n_in,
                              void* d_out, int out_size, void* d_ws, size_t ws_size,
                              hipStream_t stream) {
    (void)in_sizes; (void)n_in; (void)out_size; (void)ws_size;
    const float* x    = (const float*)d_in[0];
    const int*   ei   = (const int*)d_in[1];
    const int*   src  = ei;
    const int*   dst  = ei + NE;
    const int*   batch= (const int*)d_in[2];
    const float* rnd  = (const float*)d_in[3];
    const float* Wt   = (const float*)d_in[4];
    const float* bt   = (const float*)d_in[5];
    const float* Ws   = (const float*)d_in[6];
    const float* bs   = (const float*)d_in[7];
    float* out = (float*)d_out;

    char* w = (char*)d_ws;
    double* u  = (double*)w;
    double* c0 = (double*)(w + 1024);
    u32* counters = (u32*)(w + 2048);
    size_t off = 4096;
    double* y   = (double*)(w + off); off += (size_t)NN*8;
    u64* fkeyA  = (u64*)(w + off); off += (size_t)NE*8;
    u64* fdatA  = (u64*)(w + off); off += (size_t)NE*8;
    u64* fkeyB  = (u64*)(w + off); off += (size_t)NE*8;
    u64* fdatB  = (u64*)(w + off); off += (size_t)NE*8;
    u64* mkeyA  = (u64*)(w + off); off += (size_t)MCAP*8;
    u64* mpayA  = (u64*)(w + off); off += (size_t)MCAP*8;
    u64* combK  = (u64*)(w + off); off += (size_t)SCAP*8;
    u64* combD  = (u64*)(w + off); off += (size_t)SCAP*8;
    u64* combK2 = (u64*)(w + off); off += (size_t)SCAP*8;
    u64* combD2 = (u64*)(w + off); off += (size_t)SCAP*8;
    u64* bt0    = (u64*)(w + off); off += (size_t)NN*8;
    u64* bt1    = (u64*)(w + off); off += (size_t)NN*8;
    u32* avail  = (u32*)(w + off); off += NN/8;
    int* cl     = (int*)(w + off); off += (size_t)NN*4;
    u64* Mlist  = (u64*)(w + off); off += (size_t)NN*8;
    u32* hist   = (u32*)(w + off); off += 256*SNB*4;
    u32* mflag  = (u32*)(w + off); off += (size_t)SCAP*4;
    u32* candIdx= (u32*)(w + off); off += (size_t)SCAP*4;
    u32* csums  = (u32*)(w + off); off += 64*4;
    u32* msums  = (u32*)(w + off); off += 64*4;
    u32* slist  = (u32*)(w + off); off += (size_t)NN*4;
    u32* tkey   = (u32*)(w + off); off += (size_t)HCAP*4;
    u32* tmin   = (u32*)(w + off); off += (size_t)HCAP*4;
    u32* eslot  = (u32*)(w + off); off += (size_t)NE*4;

    ep_prep<<<1, 128, 0, stream>>>(Wt, Ws, bt, bs, u, c0, counters);
    ep_init<<<128, 256, 0, stream>>>(bt0, bt1, avail, cl);
    hipMemsetAsync(tkey, 0xFF, (size_t)HCAP*4, stream);
    hipMemsetAsync(tmin, 0xFF, (size_t)HCAP*4, stream);

    ep_ynode<<<8192, 256, 0, stream>>>(x, u, y);
    ep_escore<<<1024, 256, 0, stream>>>(src, dst, rnd, y, c0, fkeyA, fdatA, counters, out);

    // NFULL full-grid priority-matching rounds (2 dispatches each)
    u64 *fk = fkeyA, *fd = fdatA, *fk2 = fkeyB, *fd2 = fdatB;
    u64 *bc = bt0, *bn = bt1;
    for (u32 rd = 0; rd < NFULL; rd++) {
        ep_rA<<<512, 256, 0, stream>>>(fk, fd, &counters[CNT0+rd], bc, avail);
        ep_rB<<<512, 256, 0, stream>>>(fk, fd, &counters[CNT0+rd], &counters[CNT0+rd+1],
                                       fk2, fd2, bc, bn, avail, mkeyA, mpayA, counters);
        u64* tp;
        tp = fk; fk = fk2; fk2 = tp;
        tp = fd; fd = fd2; fd2 = tp;
        tp = bc; bc = bn; bn = tp;
    }

    // merge matched + remaining, sort by unique priority
    ep_merge<<<SNB, 1024, 0, stream>>>(mkeyA, mpayA, fk, fd, counters, combK, combD);
    u64 *ki = combK, *pi = combD, *ko = combK2, *po = combD2;
    for (int p = 0; p < 6; p++) {
        int shift = 16 + p*8;
        ms_hist<<<SNB, 64, 0, stream>>>(ki, hist, shift);
        ms_scan<<<1, 64, 0, stream>>>(hist);
        ms_scat<<<SNB, 64, 0, stream>>>(ki, pi, ko, po, hist, shift);
        u64* tp;
        tp = ki; ki = ko; ko = tp;
        tp = pi; pi = po; po = tp;
    }
    // 6 passes (even) -> sorted list back in combK/combD

    // candidate compaction + candidate-only claim walk + parallel cid assignment
    ep_csum<<<SNB, 1024, 0, stream>>>(combD, counters, mflag, csums);
    ep_cscan<<<1, 64, 0, stream>>>(csums, counters, 5);
    ep_cemit<<<SNB, 1024, 0, stream>>>(combD, counters, csums, candIdx);
    ep_walk<<<1, 1024, 0, stream>>>(combD, candIdx, counters, avail, mflag);
    ep_msum<<<SNB, 1024, 0, stream>>>(mflag, msums);
    ep_cscan<<<1, 64, 0, stream>>>(msums, counters, 2);
    ep_memit<<<SNB, 1024, 0, stream>>>(combD, mflag, msums, batch, Mlist, cl, out);

    ep_scanN<<<1, 1024, 0, stream>>>(cl, counters, slist, out);

    ep_init_out<<<16384, 256, 0, stream>>>(counters, out);
    ep_out_nodes<<<128, 256, 0, stream>>>(cl, batch, counters, out);

    ep_newx_m<<<512, 256, 0, stream>>>(x, Wt, bt, Mlist, counters, out);
    ep_newx_s<<<1024, 256, 0, stream>>>(x, Wt, bt, slist, counters, out);

    ep_newei<<<1024, 256, 0, stream>>>(src, dst, cl, tkey, tmin, eslot, out);
    ep_valid<<<1024, 256, 0, stream>>>(src, dst, cl, tmin, eslot, out);
}

// Round 9
// 650.045 us; speedup vs baseline: 1.5407x; 1.0238x over previous
//
#include <hip/hip_runtime.h>
#include <stdint.h>

typedef unsigned int u32;
typedef unsigned long long u64;

#define NN 32768
#define NE 262144
#define NC 128

// output element offsets (ALL FLOAT32)
#define O0 0u               // new_x [NN*128]
#define O1 4194304u         // cluster [NN]
#define O2 4227072u         // new_batch [NN]
#define O3 4259840u         // new_edge_score [NN]
#define O4 4292608u         // num_clusters [1]
#define O5 4292609u         // new_ei [2*NE]
#define O6 4816897u         // edge_valid [NE]
#define O7 5079041u         // e [NE]

#define HCAP (1u<<19)
#define NFULL 8
#define CNT0 8
#define MCAP 16384
#define SCAP 32768
#define SNB 32
#define MAXK 0xFFFFFFFFFFFFFFFFull
#define PREFLAG (1ull<<62)

// ---------------- init: prep (block 0) + all per-call state (inert fusion) ---------
__global__ void ep_init(const float* Wt, const float* Ws, const float* bt, const float* bs,
                        double* u, double* c0, u32* counters,
                        u64* b0, u64* b1, u32* avail, int* cl,
                        u32* tkey, u32* tmin) {
    u32 i = blockIdx.x*blockDim.x + threadIdx.x; // 512*256 = 131072
    if (blockIdx.x == 0 && threadIdx.x < 128) {
        int r = threadIdx.x;
        double s = 0.0;
        for (int j = 0; j < NC; j++) s += (double)Wt[r*NC+j] * (double)Ws[j];
        u[r] = s;
        if (r == 0) {
            double c = 0.0;
            for (int j = 0; j < NC; j++) c += (double)bt[j] * (double)Ws[j];
            *c0 = c + (double)bs[0];
        }
    }
    if (i < 64) counters[i] = 0u;
    if (i < NN) { b0[i] = MAXK; b1[i] = MAXK; cl[i] = -1; }
    if (i < NN/32) avail[i] = 0xFFFFFFFFu;
    for (u32 j = i; j < HCAP; j += 131072u) { tkey[j] = 0xFFFFFFFFu; tmin[j] = 0xFFFFFFFFu; }
}

// ---------------- per-node f64 dot y[v] = x[v,:]·u ----------------
__global__ void ep_ynode(const float* x, const double* u, double* y) {
    int gid = blockIdx.x*blockDim.x + threadIdx.x;
    int v = gid >> 6, lane = threadIdx.x & 63;
    if (v >= NN) return;
    double t = (double)x[v*NC+lane]*u[lane] + (double)x[v*NC+lane+64]*u[lane+64];
    for (int off = 32; off; off >>= 1) t += __shfl_down(t, off, 64);
    if (lane == 0) y[v] = t;
}

// ---------------- per-edge score + unique priority + frontier push (R6-exact) -------
__global__ void ep_escore(const int* src, const int* dst, const float* rnd, const double* y,
                          const double* c0, u64* fkey, u64* fdat, u32* counters, float* out) {
    int e = blockIdx.x*blockDim.x + threadIdx.x;
    if (e >= NE) return;
    int s = src[e], d = dst[e];
    double z = y[s] + y[d] + *c0;
    double sc = 1.0/(1.0 + exp(-z));
    out[O7 + e] = (float)sc;
    u64 b = (u64)__double_as_longlong(z);
    u64 ord = (b & 0x8000000000000000ull) ? ~b : (b | 0x8000000000000000ull); // ascending z
    u64 P = ((~ord) & 0xFFFFFFFFFFFC0000ull) | (u64)(u32)e; // 46b score desc | 18b idx (unique)
    if ((double)rnd[e] <= sc) {
        u32 p = atomicAdd(&counters[CNT0], 1u);
        fkey[p] = P;
        fdat[p] = ((u64)(u32)e << 30) | ((u64)(u32)s << 15) | (u64)(u32)d;
    }
}

// ---------------- full-grid priority-matching rounds (R6-exact, 2-buffer ping-pong) -
__device__ __forceinline__ bool ep_bit(const u32* a, u32 v) { return (a[v>>5] >> (v&31)) & 1u; }

__global__ void ep_rA(const u64* fkey, const u64* fdat, const u32* cnt, u64* bt, const u32* avail) {
    u32 n = *cnt;
    for (u32 i = blockIdx.x*blockDim.x + threadIdx.x; i < n; i += 131072u) {
        u64 v = fdat[i];
        u32 s = (u32)((v>>15)&0x7FFF), d = (u32)(v&0x7FFF);
        if (ep_bit(avail, s) && ep_bit(avail, d)) {
            u64 P = fkey[i];
            atomicMin(&bt[s], P); atomicMin(&bt[d], P);
        }
    }
}

__global__ void ep_rB(const u64* fkey, const u64* fdat, const u32* cnt, u32* cntN,
                      u64* fkeyN, u64* fdatN, const u64* bt, u64* btN, u32* avail,
                      u64* mkey, u64* mpay, u32* counters) {
    u32 n = *cnt;
    for (u32 i = blockIdx.x*blockDim.x + threadIdx.x; i < n; i += 131072u) {
        u64 v = fdat[i];
        u32 s = (u32)((v>>15)&0x7FFF), d = (u32)(v&0x7FFF);
        if (!ep_bit(avail, s) || !ep_bit(avail, d)) continue; // dead
        u64 P = fkey[i];
        if (bt[s] == P && bt[d] == P) {
            u32 slot = atomicAdd(&counters[2], 1u);
            mkey[slot] = P; mpay[slot] = v;
            atomicAnd(&avail[s>>5], ~(1u<<(s&31)));
            atomicAnd(&avail[d>>5], ~(1u<<(d&31)));
        } else {
            u32 p = atomicAdd(cntN, 1u);
            fkeyN[p] = P; fdatN[p] = v;
            btN[s] = MAXK; btN[d] = MAXK;  // pre-reset next round's buffer
        }
    }
}

// ---------------- merge matched + remaining into one padded sort list ----------------
__global__ void ep_merge(const u64* mk, const u64* mp, const u64* fk, const u64* fd,
                         u32* counters, u64* ck, u64* cd2) {
    u32 i = blockIdx.x*blockDim.x + threadIdx.x; // SNB*1024 threads
    u32 nm0 = counters[2];
    u32 cr  = counters[CNT0+NFULL];
    if (i == 0) { u32 tot = nm0 + cr; counters[4] = tot > SCAP ? SCAP : tot; }
    u64 K = MAXK, D = 0;
    if (i < nm0) { K = mk[i]; D = mp[i] | PREFLAG; }
    else if (i < nm0 + cr && i < SCAP) { K = fk[i-nm0]; D = fd[i-nm0]; }
    ck[i] = K; cd2[i] = D;
}

// ---------------- radix sort (R6-exact): hist / scan / scatter ----------------
__global__ void ms_hist(const u64* key, u32* hist, int shift) {
    __shared__ u32 h[256];
    int t = threadIdx.x; // 64 threads, SNB blocks
    for (int i = t; i < 256; i += 64) h[i] = 0;
    __syncthreads();
    int base = blockIdx.x*1024 + t*16;
    for (int j = 0; j < 16; j++) {
        u32 dg = (u32)(key[base+j] >> shift) & 255u;
        atomicAdd(&h[dg], 1u);
    }
    __syncthreads();
    for (int i = t; i < 256; i += 64) hist[i*SNB + blockIdx.x] = h[i];
}

__global__ void ms_scan(u32* hist) { // 256*SNB entries, 1 block x 64 threads
    int t = threadIdx.x;
    int per = 256*SNB/64;
    int base = t*per;
    u32 s = 0;
    for (int j = 0; j < per; j++) s += hist[base+j];
    u32 x = s;
    for (int off = 1; off < 64; off <<= 1) { u32 yv = __shfl_up(x, off, 64); if (t >= off) x += yv; }
    u32 run = x - s;
    for (int j = 0; j < per; j++) { u32 tmp = hist[base+j]; hist[base+j] = run; run += tmp; }
}

__global__ void ms_scat(const u64* ki, const u64* pi, u64* ko, u64* po, const u32* hist, int shift) {
    __shared__ unsigned short m[256][64]; // 32 KiB
    int t = threadIdx.x; // 64 threads, SNB blocks
    for (int i = t; i < 256*32; i += 64) ((u32*)m)[i] = 0u;
    __syncthreads();
    int base = blockIdx.x*1024 + t*16;
    u64 kr[16]; u32 dg[16];
    #pragma unroll
    for (int j = 0; j < 16; j++) {
        kr[j] = ki[base+j];
        dg[j] = (u32)(kr[j] >> shift) & 255u;
        m[dg[j]][t]++;
    }
    __syncthreads();
    for (int k = 0; k < 4; k++) {
        int d = t*4 + k;
        u32 run = 0;
        for (int tt = 0; tt < 64; tt++) { u32 tmp = m[d][tt]; m[d][tt] = (unsigned short)run; run += tmp; }
    }
    __syncthreads();
    #pragma unroll
    for (int j = 0; j < 16; j++) {
        u32 d = dg[j];
        u32 pos = hist[d*SNB + blockIdx.x] + m[d][t];
        m[d][t]++;
        ko[pos] = kr[j];
        po[pos] = pi[base+j];
    }
}

// ---------------- candidate compaction over sorted list (R6-exact) ----------------
__global__ void ep_csum(const u64* sd, const u32* counters, u32* mflag, u32* csums) {
    u32 i = blockIdx.x*1024 + threadIdx.x;
    u32 cnt = counters[4];
    u64 v = sd[i];
    bool pre = (i < cnt) && ((v & PREFLAG) != 0);
    bool cand = (i < cnt) && !pre;
    mflag[i] = pre ? 1u : 0u;
    int c = __syncthreads_count(cand ? 1 : 0);
    if (threadIdx.x == 0) csums[blockIdx.x] = (u32)c;
}

__global__ void ep_cscan(u32* csums, u32* counters, int which) { // scans SNB values, 1 wave
    int t = threadIdx.x; // 64
    u32 v = (t < SNB) ? csums[t] : 0u;
    u32 x = v;
    for (int off = 1; off < 64; off <<= 1) { u32 y = __shfl_up(x, off, 64); if (t >= off) x += y; }
    if (t < SNB) csums[t] = x - v;
    if (t == SNB-1) counters[which] = x;
}

__global__ void ep_cemit(const u64* sd, const u32* counters, const u32* csums, u32* candIdx) {
    __shared__ u32 w[16];
    int t = threadIdx.x;
    u32 i = blockIdx.x*1024 + t;
    u32 cnt = counters[4];
    u64 v = sd[i];
    bool pre = (i < cnt) && ((v & PREFLAG) != 0);
    u32 c = ((i < cnt) && !pre) ? 1u : 0u;
    u32 x = c;
    for (int off = 1; off < 64; off <<= 1) { u32 y = __shfl_up(x, off, 64); if ((t&63) >= off) x += y; }
    if ((t&63) == 63) w[t>>6] = x;
    __syncthreads();
    if (t < 16) {
        u32 ww = w[t];
        for (int off = 1; off < 16; off <<= 1) { u32 y = __shfl_up(ww, off, 16); if (t >= off) ww += y; }
        w[t] = ww;
    }
    __syncthreads();
    u32 excl = ((t>>6) ? w[(t>>6)-1] : 0u) + x - c;
    if (c) candIdx[csums[blockIdx.x] + excl] = i;
}

// ---------------- R6-exact candidate-only sorted claim walk (single block, LDS) -----
__global__ void __launch_bounds__(1024) ep_walk(const u64* sd, const u32* candIdx,
                                                const u32* counters, const u32* availG,
                                                u32* mflag) {
    __shared__ u32 avail[1024];       // 32768 bits
    __shared__ u32 claim[16384];      // 64 KiB claim table (node & 16383)
    int t = threadIdx.x;
    avail[t] = availG[t];
    for (int j = t; j < 16384; j += 1024) claim[j] = 0xFFFFFFFFu;
    __syncthreads();
    u32 ncand = counters[5];
    for (u32 base = 0; base < ncand; base += 1024) {
        u32 j = base + t;
        bool have = j < ncand;
        u32 i = 0, s = 0, d = 0;
        if (have) {
            i = candIdx[j];
            u64 v = sd[i];
            s = (u32)((v>>15)&0x7FFF); d = (u32)(v&0x7FFF);
        }
        int st;
        if (!have) st = 1;
        else st = (((avail[s>>5]>>(s&31))&1u) && ((avail[d>>5]>>(d&31))&1u)) ? 0 : 1;
        for (int it = 0; __syncthreads_count(st == 0) > 0 && it < 300; it++) {
            u32 hs = s & 16383u, hd = d & 16383u;
            bool wrote = false;
            if (st == 0) { atomicMin(&claim[hs], (u32)t); atomicMin(&claim[hd], (u32)t); wrote = true; }
            __syncthreads();
            if (st == 0 && claim[hs] == (u32)t && claim[hd] == (u32)t) {
                st = 2;
                atomicAnd(&avail[s>>5], ~(1u<<(s&31)));
                atomicAnd(&avail[d>>5], ~(1u<<(d&31)));
            }
            __syncthreads();
            if (wrote) { claim[hs] = 0xFFFFFFFFu; claim[hd] = 0xFFFFFFFFu; }
            if (st == 0) {
                if (!((avail[s>>5]>>(s&31))&1u) || !((avail[d>>5]>>(d&31))&1u)) st = 1;
            }
        }
        if (st == 2) mflag[i] = 1u;
        __syncthreads();
    }
}

// ---------------- cid assignment: parallel scan over match flags (R6-exact) ---------
__global__ void ep_msum(const u32* mflag, u32* msums) {
    u32 i = blockIdx.x*1024 + threadIdx.x;
    int c = __syncthreads_count(mflag[i] != 0 ? 1 : 0);
    if (threadIdx.x == 0) msums[blockIdx.x] = (u32)c;
}

__global__ void ep_memit(const u64* sd, const u32* mflag, const u32* msums,
                         const int* batch, u64* Mlist, int* cl, float* out) {
    __shared__ u32 w[16];
    int t = threadIdx.x;
    u32 i = blockIdx.x*1024 + t;
    u32 m = mflag[i];
    u32 x = m;
    for (int off = 1; off < 64; off <<= 1) { u32 y = __shfl_up(x, off, 64); if ((t&63) >= off) x += y; }
    if ((t&63) == 63) w[t>>6] = x;
    __syncthreads();
    if (t < 16) {
        u32 ww = w[t];
        for (int off = 1; off < 16; off <<= 1) { u32 y = __shfl_up(ww, off, 16); if (t >= off) ww += y; }
        w[t] = ww;
    }
    __syncthreads();
    u32 excl = ((t>>6) ? w[(t>>6)-1] : 0u) + x - m;
    if (m) {
        u32 cid = msums[blockIdx.x] + excl;
        u64 v = sd[i] & ~PREFLAG;
        u32 e = (u32)(v>>30), s = (u32)((v>>15)&0x7FFF), d = (u32)(v&0x7FFF);
        Mlist[cid] = v;
        cl[s] = (int)cid; cl[d] = (int)cid;
        u32 mx = s > d ? s : d; // last-writer-wins = max node index
        out[O2 + cid] = (float)batch[mx];
        out[O3 + cid] = out[O7 + e];
    }
}

// ---------------- singleton cid assignment + compacted singleton list ----------------
__global__ void ep_scanN(int* cl, u32* counters, u32* slist, float* out) {
    __shared__ u32 w[16];
    int t = threadIdx.x;
    int base = t*32;
    u32 s = 0;
    for (int j = 0; j < 32; j++) s += (cl[base+j] < 0) ? 1u : 0u;
    u32 x = s;
    for (int off = 1; off < 64; off <<= 1) { u32 y = __shfl_up(x, off, 64); if ((t&63) >= off) x += y; }
    if ((t&63) == 63) w[t>>6] = x;
    __syncthreads();
    if (t < 16) {
        u32 ww = w[t];
        for (int off = 1; off < 16; off <<= 1) { u32 y = __shfl_up(ww, off, 16); if (t >= off) ww += y; }
        w[t] = ww;
    }
    __syncthreads();
    u32 excl = ((t>>6) ? w[(t>>6)-1] : 0u) + x - s;
    u32 total = w[15];
    u32 nm = counters[2];
    if (t == 0) {
        counters[3] = nm + total;
        counters[6] = total;
        out[O4] = (float)(nm + total);
    }
    u32 run = nm + excl;
    for (int j = 0; j < 32; j++) {
        if (cl[base+j] < 0) {
            slist[run - nm] = (u32)(base + j);
            cl[base+j] = (int)(run++);
        }
    }
}

// ---------------- cluster ids + O2/O3 tails (inert fusion) ----------------
__global__ void ep_out_nodes(const int* cl, const int* batch, const u32* counters, float* out) {
    int v = blockIdx.x*blockDim.x + threadIdx.x;
    if (v >= NN) return;
    u32 nm = counters[2], ncl = counters[3];
    int c = cl[v];
    out[O1 + v] = (float)c;
    if (c >= (int)nm) out[O2 + c] = (float)batch[v]; // singleton batch
    if (v >= (int)nm) out[O3 + v] = 1.0f;            // default edge score
    if (v >= (int)ncl) out[O2 + v] = 0.0f;           // batch tail zeros
}

// ---------------- new_x matched rows ----------------
__global__ void ep_newx_m(const float* x, const float* Wt, const float* bt,
                          const u64* Mlist, const u32* counters, float* out) {
    __shared__ u64 ml[32];
    __shared__ float m[32][128];
    u32 nm = counters[2];
    u32 base = blockIdx.x * 32u;
    if (base >= nm) return;
    int t = threadIdx.x, lane = t & 63, wv = t >> 6;
    if (t < 32) { u32 r = base + (u32)t; ml[t] = (r < nm) ? Mlist[r] : 0ull; }
    __syncthreads();
    for (int i = t; i < 4096; i += 256) {
        int r = i >> 7, k = i & 127;
        u64 v = ml[r];
        u32 s = (u32)((v>>15)&0x7FFF), d = (u32)(v&0x7FFF);
        m[r][k] = x[s*NC+k] + x[d*NC+k];
    }
    __syncthreads();
    float a0[8], a1[8];
    #pragma unroll
    for (int r = 0; r < 8; r++) { a0[r] = bt[lane]; a1[r] = bt[lane+64]; }
    for (int k = 0; k < 128; k++) {
        float w0 = Wt[k*NC+lane], w1 = Wt[k*NC+lane+64];
        #pragma unroll
        for (int r = 0; r < 8; r++) { float mm = m[wv*8+r][k]; a0[r] += mm*w0; a1[r] += mm*w1; }
    }
    #pragma unroll
    for (int r = 0; r < 8; r++) {
        u32 row = base + (u32)(wv*8 + r);
        if (row < nm) {
            out[O0 + (size_t)row*NC + lane]      = a0[r];
            out[O0 + (size_t)row*NC + lane + 64] = a1[r];
        }
    }
}

// ---------------- new_x singleton rows + zero tail (inert fusion) ----------------
__global__ void ep_newx_s(const float* x, const float* Wt, const float* bt,
                          const u32* slist, const u32* counters, float* out) {
    __shared__ u32 nodes[32];
    __shared__ float m[32][128];
    u32 nm = counters[2], ncl = counters[3], sc = counters[6];
    u32 base = nm + blockIdx.x * 32u; // grid 1024 blocks covers rows [nm, nm+32768)
    if (base >= NN) return;
    int t = threadIdx.x, lane = t & 63, wv = t >> 6;
    if (base >= ncl) { // pure zero rows
        for (int i = t; i < 4096; i += 256) {
            u32 row = base + (u32)(i >> 7);
            if (row < NN) out[O0 + (size_t)row*NC + (i & 127)] = 0.0f;
        }
        return;
    }
    if (t < 32) { u32 p = base - nm + (u32)t; nodes[t] = (p < sc) ? slist[p] : slist[0]; }
    __syncthreads();
    for (int i = t; i < 4096; i += 256) {
        int r = i >> 7, k = i & 127;
        m[r][k] = 2.0f * x[nodes[r]*NC + k];
    }
    __syncthreads();
    float a0[8], a1[8];
    #pragma unroll
    for (int r = 0; r < 8; r++) { a0[r] = bt[lane]; a1[r] = bt[lane+64]; }
    for (int k = 0; k < 128; k++) {
        float w0 = Wt[k*NC+lane], w1 = Wt[k*NC+lane+64];
        #pragma unroll
        for (int r = 0; r < 8; r++) { float mm = m[wv*8+r][k]; a0[r] += mm*w0; a1[r] += mm*w1; }
    }
    #pragma unroll
    for (int r = 0; r < 8; r++) {
        u32 row = base + (u32)(wv*8 + r);
        if (row >= NN) continue;
        if (row < ncl) {
            out[O0 + (size_t)row*NC + lane]      = a0[r];
            out[O0 + (size_t)row*NC + lane + 64] = a1[r];
        } else {
            out[O0 + (size_t)row*NC + lane]      = 0.0f;
            out[O0 + (size_t)row*NC + lane + 64] = 0.0f;
        }
    }
}

// ---------------- new_ei + edge_valid via min-index hash ----------------
__global__ void ep_newei(const int* src, const int* dst, const int* cl,
                         u32* tkey, u32* tmin, u32* eslot, float* out) {
    int e = blockIdx.x*blockDim.x + threadIdx.x;
    if (e >= NE) return;
    u32 cs = (u32)cl[src[e]], cd = (u32)cl[dst[e]];
    out[O5 + e]      = (float)cs;
    out[O5 + NE + e] = (float)cd;
    u32 key = (cs << 15) | cd;
    u32 slot = ((key * 2654435761u) >> 11) & (HCAP-1);
    while (true) {
        u32 k = tkey[slot];
        if (k == key) break;
        if (k == 0xFFFFFFFFu) {
            u32 old = atomicCAS(&tkey[slot], 0xFFFFFFFFu, key);
            if (old == 0xFFFFFFFFu || old == key) break;
        }
        slot = (slot + 1) & (HCAP-1);
    }
    eslot[e] = slot | ((cs != cd) ? 0x80000000u : 0u);
    atomicMin(&tmin[slot], (u32)e);
}

__global__ void ep_valid(const u32* tmin, const u32* eslot, float* out) {
    int e = blockIdx.x*blockDim.x + threadIdx.x;
    if (e >= NE) return;
    u32 sl = eslot[e];
    bool valid = (tmin[sl & 0x7FFFFFFFu] == (u32)e) && (sl >> 31);
    out[O6 + e] = valid ? 1.0f : 0.0f;
}

// =============================== host ===============================
extern "C" void kernel_launch(void* const* d_in, const int* in_sizes, int n_in,
                              void* d_out, int out_size, void* d_ws, size_t ws_size,
                              hipStream_t stream) {
    (void)in_sizes; (void)n_in; (void)out_size; (void)ws_size;
    const float* x    = (const float*)d_in[0];
    const int*   ei   = (const int*)d_in[1];
    const int*   src  = ei;
    const int*   dst  = ei + NE;
    const int*   batch= (const int*)d_in[2];
    const float* rnd  = (const float*)d_in[3];
    const float* Wt   = (const float*)d_in[4];
    const float* bt   = (const float*)d_in[5];
    const float* Ws   = (const float*)d_in[6];
    const float* bs   = (const float*)d_in[7];
    float* out = (float*)d_out;

    char* w = (char*)d_ws;
    double* u  = (double*)w;
    double* c0 = (double*)(w + 1024);
    u32* counters = (u32*)(w + 2048);
    size_t off = 4096;
    double* y   = (double*)(w + off); off += (size_t)NN*8;
    u64* fkeyA  = (u64*)(w + off); off += (size_t)NE*8;
    u64* fdatA  = (u64*)(w + off); off += (size_t)NE*8;
    u64* fkeyB  = (u64*)(w + off); off += (size_t)NE*8;
    u64* fdatB  = (u64*)(w + off); off += (size_t)NE*8;
    u64* mkeyA  = (u64*)(w + off); off += (size_t)MCAP*8;
    u64* mpayA  = (u64*)(w + off); off += (size_t)MCAP*8;
    u64* combK  = (u64*)(w + off); off += (size_t)SCAP*8;
    u64* combD  = (u64*)(w + off); off += (size_t)SCAP*8;
    u64* combK2 = (u64*)(w + off); off += (size_t)SCAP*8;
    u64* combD2 = (u64*)(w + off); off += (size_t)SCAP*8;
    u64* bt0    = (u64*)(w + off); off += (size_t)NN*8;
    u64* bt1    = (u64*)(w + off); off += (size_t)NN*8;
    u32* avail  = (u32*)(w + off); off += NN/8;
    int* cl     = (int*)(w + off); off += (size_t)NN*4;
    u64* Mlist  = (u64*)(w + off); off += (size_t)NN*8;
    u32* hist   = (u32*)(w + off); off += 8192*4;
    u32* mflag  = (u32*)(w + off); off += (size_t)SCAP*4;
    u32* candIdx= (u32*)(w + off); off += (size_t)SCAP*4;
    u32* csums  = (u32*)(w + off); off += 64*4;
    u32* msums  = (u32*)(w + off); off += 64*4;
    u32* slist  = (u32*)(w + off); off += (size_t)NN*4;
    u32* tkey   = (u32*)(w + off); off += (size_t)HCAP*4;
    u32* tmin   = (u32*)(w + off); off += (size_t)HCAP*4;
    u32* eslot  = (u32*)(w + off); off += (size_t)NE*4;

    ep_init<<<512, 256, 0, stream>>>(Wt, Ws, bt, bs, u, c0, counters,
                                     bt0, bt1, avail, cl, tkey, tmin);
    ep_ynode<<<8192, 256, 0, stream>>>(x, u, y);
    ep_escore<<<1024, 256, 0, stream>>>(src, dst, rnd, y, c0, fkeyA, fdatA, counters, out);

    // R6-exact: NFULL rounds of (rA, rB) with 2-buffer ping-pong bestT
    u64 *fk = fkeyA, *fd = fdatA, *fk2 = fkeyB, *fd2 = fdatB;
    u64 *bc = bt0, *bn = bt1;
    for (u32 rd = 0; rd < NFULL; rd++) {
        ep_rA<<<512, 256, 0, stream>>>(fk, fd, &counters[CNT0+rd], bc, avail);
        ep_rB<<<512, 256, 0, stream>>>(fk, fd, &counters[CNT0+rd], &counters[CNT0+rd+1],
                                       fk2, fd2, bc, bn, avail, mkeyA, mpayA, counters);
        u64* tp;
        tp = fk; fk = fk2; fk2 = tp;
        tp = fd; fd = fd2; fd2 = tp;
        tp = bc; bc = bn; bn = tp;
    }

    ep_merge<<<SNB, 1024, 0, stream>>>(mkeyA, mpayA, fk, fd, counters, combK, combD);
    u64 *ki = combK, *pi = combD, *ko = combK2, *po = combD2;
    for (int p = 0; p < 6; p++) {
        int shift = 16 + p*8;
        ms_hist<<<SNB, 64, 0, stream>>>(ki, hist, shift);
        ms_scan<<<1, 64, 0, stream>>>(hist);
        ms_scat<<<SNB, 64, 0, stream>>>(ki, pi, ko, po, hist, shift);
        u64* tp;
        tp = ki; ki = ko; ko = tp;
        tp = pi; pi = po; po = tp;
    }
    // 6 passes (even) -> sorted list in combK/combD

    ep_csum<<<SNB, 1024, 0, stream>>>(combD, counters, mflag, csums);
    ep_cscan<<<1, 64, 0, stream>>>(csums, counters, 5);
    ep_cemit<<<SNB, 1024, 0, stream>>>(combD, counters, csums, candIdx);
    ep_walk<<<1, 1024, 0, stream>>>(combD, candIdx, counters, avail, mflag);
    ep_msum<<<SNB, 1024, 0, stream>>>(mflag, msums);
    ep_cscan<<<1, 64, 0, stream>>>(msums, counters, 2);
    ep_memit<<<SNB, 1024, 0, stream>>>(combD, mflag, msums, batch, Mlist, cl, out);

    ep_scanN<<<1, 1024, 0, stream>>>(cl, counters, slist, out);
    ep_out_nodes<<<128, 256, 0, stream>>>(cl, batch, counters, out);

    ep_newx_m<<<512, 256, 0, stream>>>(x, Wt, bt, Mlist, counters, out);
    ep_newx_s<<<1024, 256, 0, stream>>>(x, Wt, bt, slist, counters, out);

    ep_newei<<<1024, 256, 0, stream>>>(src, dst, cl, tkey, tmin, eslot, out);
    ep_valid<<<1024, 256, 0, stream>>>(tmin, eslot, out);
}